// Round 10
// baseline (6424.698 us; speedup 1.0000x reference)
//
#include <hip/hip_runtime.h>
#include <hip/hip_bf16.h>
#include <math.h>

// ---- problem dims ----
constexpr int NB   = 32;
constexpr int NS   = 256;
constexpr int NLC  = 16;
constexpr int NWD  = 256;
constexpr int NCD  = 124;
constexpr int NCO  = 32;
constexpr int NPOS = 36;
constexpr int NENR = 7;
constexpr int NH   = 512;
constexpr int NT   = 18;
constexpr int NIN0 = 331;
constexpr int NIN0P= 352;    // padded to x32 for BK=32
constexpr int NIN1 = 1024;
constexpr int NBS  = NB*NS;  // 8192
constexpr int NG4  = 4*NH;   // 2048
constexpr int NHID = 128;
constexpr int NCHUNK = 16;   // unit-chunks per dir (32 units each)

typedef __attribute__((ext_vector_type(8))) short short8v;
typedef __attribute__((ext_vector_type(4))) float f32x4;

__device__ __forceinline__ float sigmoidf_(float x){ return 1.0f/(1.0f+expf(-x)); }
__device__ __forceinline__ short f2bf(float f) {
    union { __hip_bfloat16 h; short s; } u;
    u.h = __float2bfloat16(f);
    return u.s;
}
__device__ __forceinline__ float bf2f(short s) {
    union { unsigned u; float f; } v;
    v.u = ((unsigned)(unsigned short)s) << 16;
    return v.f;
}
__device__ __forceinline__ unsigned packbf3(float v) {
    short hi = f2bf(v);
    short lo = f2bf(v - bf2f(hi));
    return ((unsigned)(unsigned short)hi << 16) | (unsigned short)lo;
}
// 8 packed u32 (elems k..k+7) -> hi/lo bf16 fragments
__device__ __forceinline__ void unpack8(const unsigned* w, short8v& hi, short8v& lo) {
    union U { short8v s; unsigned u[4]; } H, L;
    #pragma unroll
    for (int i = 0; i < 4; i++) {
        H.u[i] = (w[2*i+1] & 0xFFFF0000u) | (w[2*i] >> 16);
        L.u[i] = (w[2*i+1] << 16) | (w[2*i] & 0xFFFFu);
    }
    hi = H.s; lo = L.s;
}
// relaxed agent-scope ops (sc1 path, no cache maintenance) — proven in r6
__device__ __forceinline__ unsigned ld_sc1(const unsigned* p) {
    return __hip_atomic_load(p, __ATOMIC_RELAXED, __HIP_MEMORY_SCOPE_AGENT);
}
__device__ __forceinline__ unsigned long long ld64_sc1(const void* p) {
    return __hip_atomic_load((const unsigned long long*)p, __ATOMIC_RELAXED,
                             __HIP_MEMORY_SCOPE_AGENT);
}
__device__ __forceinline__ void st_sc1(unsigned* p, unsigned v) {
    __hip_atomic_store(p, v, __ATOMIC_RELAXED, __HIP_MEMORY_SCOPE_AGENT);
}

// ---------------- features: word embed + char CNN + concat + relu -> packed u32 ----
__global__ __launch_bounds__(128) void k_features(const int* __restrict__ x_word,
    const float* __restrict__ x_pos, const int* __restrict__ x_char,
    const float* __restrict__ x_enr, const float* __restrict__ wembW,
    const float* __restrict__ cembW, const float* __restrict__ cnnW,
    const float* __restrict__ cnnb, unsigned* __restrict__ xout)
{
    __shared__ float ce[NLC][NCD];
    __shared__ float cv[NCO][13];
    __shared__ float cpool[NCO];
    int n = blockIdx.x;
    int tid = threadIdx.x;
    for (int i = tid; i < NLC*NCD; i += 128) {
        int l = i / NCD, c = i % NCD;
        ce[l][c] = cembW[x_char[n*NLC + l]*NCD + c];
    }
    __syncthreads();
    for (int p = tid; p < NCO*12; p += 128) {
        int o = p & 31, t = p >> 5;
        const float* wr = cnnW + o*NCD*5;
        float acc = 0.f;
        for (int c = 0; c < NCD; c++) {
            #pragma unroll
            for (int k = 0; k < 5; k++) acc += ce[t+k][c] * wr[c*5+k];
        }
        cv[o][t] = acc;
    }
    __syncthreads();
    if (tid < NCO) {
        float m = cv[tid][0];
        #pragma unroll
        for (int t = 1; t < 12; t++) m = fmaxf(m, cv[tid][t]);
        cpool[tid] = m + cnnb[tid];
    }
    __syncthreads();
    int widx = x_word[n];
    unsigned* xr = xout + (size_t)n * NIN0P;
    for (int j = tid; j < NIN0P; j += 128) {
        float v;
        if (j < NWD)            v = wembW[(size_t)widx*NWD + j];
        else if (j < NWD+NPOS)  v = x_pos[n*NPOS + (j-NWD)];
        else if (j < NWD+NPOS+NCO) v = cpool[j-(NWD+NPOS)];
        else if (j < NIN0)      v = x_enr[n*NENR + (j-(NWD+NPOS+NCO))];
        else                    v = 0.f;   // K pad
        xr[j] = packbf3(fmaxf(v, 0.f));
    }
}

// ---------------- pack f32 weight [N][Ksrc] -> packed u32 [N][Kdst] (zero pad) ----
__global__ void k_pack_w(const float* __restrict__ W, unsigned* __restrict__ out,
                         int N, int Ksrc, int Kdst)
{
    int idx = blockIdx.x*256 + threadIdx.x;
    if (idx >= N*Kdst) return;
    int n = idx / Kdst, k = idx % Kdst;
    float v = (k < Ksrc) ? W[(size_t)n*Ksrc + k] : 0.f;
    out[idx] = packbf3(v);
}

// ---------------- bf16x3 MFMA GEMM: C[M,N] = A@W^T + bias ----------------
constexpr int TBK = 32;
constexpr int LSTR = 36;
__global__ __launch_bounds__(256, 2) void k_gemm_bf3(
    const unsigned* __restrict__ A, const unsigned* __restrict__ W,
    const float* __restrict__ bias, float* __restrict__ C,
    int M, int N, int K)
{
    __shared__ unsigned Asl[128*LSTR];
    __shared__ unsigned Bsl[128*LSTR];
    int bm = blockIdx.x*128, bn = blockIdx.y*128;
    int tid = threadIdx.x;
    int l = tid & 63, wv = tid >> 6;
    int wm = wv >> 1, wn = wv & 1;
    int lr = l & 15, lk = l >> 4;

    f32x4 acc[4][4];
    #pragma unroll
    for (int i = 0; i < 4; i++)
        #pragma unroll
        for (int j = 0; j < 4; j++) acc[i][j] = (f32x4){0.f,0.f,0.f,0.f};

    uint4 ra[4], rb[4];
    int KT = K / TBK;
    #pragma unroll
    for (int i = 0; i < 4; i++) {
        int idx = i*256 + tid, row = idx >> 3, c4 = (idx & 7)*4;
        ra[i] = *(const uint4*)(A + (size_t)(bm+row)*K + c4);
        rb[i] = *(const uint4*)(W + (size_t)(bn+row)*K + c4);
    }
    for (int kt = 0; kt < KT; kt++) {
        #pragma unroll
        for (int i = 0; i < 4; i++) {
            int idx = i*256 + tid, row = idx >> 3, c4 = (idx & 7)*4;
            *(uint4*)&Asl[row*LSTR + c4] = ra[i];
            *(uint4*)&Bsl[row*LSTR + c4] = rb[i];
        }
        __syncthreads();
        if (kt+1 < KT) {
            #pragma unroll
            for (int i = 0; i < 4; i++) {
                int idx = i*256 + tid, row = idx >> 3, c4 = (idx & 7)*4;
                ra[i] = *(const uint4*)(A + (size_t)(bm+row)*K + (kt+1)*TBK + c4);
                rb[i] = *(const uint4*)(W + (size_t)(bn+row)*K + (kt+1)*TBK + c4);
            }
        }
        short8v Ah[4], Al_[4], Bh[4], Bl[4];
        #pragma unroll
        for (int f = 0; f < 4; f++) {
            unsigned w8[8];
            int rowA = wm*64 + f*16 + lr;
            *(uint4*)&w8[0] = *(const uint4*)&Asl[rowA*LSTR + lk*8];
            *(uint4*)&w8[4] = *(const uint4*)&Asl[rowA*LSTR + lk*8 + 4];
            unpack8(w8, Ah[f], Al_[f]);
            int rowB = wn*64 + f*16 + lr;
            *(uint4*)&w8[0] = *(const uint4*)&Bsl[rowB*LSTR + lk*8];
            *(uint4*)&w8[4] = *(const uint4*)&Bsl[rowB*LSTR + lk*8 + 4];
            unpack8(w8, Bh[f], Bl[f]);
        }
        #pragma unroll
        for (int i = 0; i < 4; i++)
            #pragma unroll
            for (int j = 0; j < 4; j++) {
                acc[i][j] = __builtin_amdgcn_mfma_f32_16x16x32_bf16(Ah[i],  Bh[j], acc[i][j], 0, 0, 0);
                acc[i][j] = __builtin_amdgcn_mfma_f32_16x16x32_bf16(Al_[i], Bh[j], acc[i][j], 0, 0, 0);
                acc[i][j] = __builtin_amdgcn_mfma_f32_16x16x32_bf16(Ah[i],  Bl[j], acc[i][j], 0, 0, 0);
            }
        __syncthreads();
    }
    #pragma unroll
    for (int i = 0; i < 4; i++) {
        int m0 = bm + wm*64 + i*16 + lk*4;
        #pragma unroll
        for (int j = 0; j < 4; j++) {
            int n0 = bn + wn*64 + j*16 + lr;
            float bv = bias[n0];
            #pragma unroll
            for (int q = 0; q < 4; q++)
                C[(size_t)(m0+q)*N + n0] = acc[i][j][q] + bv;
        }
    }
}

// ---------------- persistent LSTM layer: 2 dirs x 16 chunks, 512 thr ----------
// 8 waves = 4 gates x 2 K-halves. launch_bounds(512,1): 1 block/CU -> 256-VGPR
// cap; weights (128 VGPR) stay RESIDENT (r9's (512,2) capped at 128 and the
// compiler rematerialized weights from global every step — the 2-3us/step gap).
// Swizzle col^((row&7)<<1): 8 bank-groups x 8 lanes = conflict-free MFMA reads.
// Exchange discipline (r6-proven): relaxed agent-scope (sc1) only; per-wave
// vmcnt(0)+flag release; grid (2,16) puts each dir's sync domain on 4 XCDs.
__global__ __launch_bounds__(512, 1) void k_lstm_layer(
    const float* __restrict__ zx_f, const float* __restrict__ zx_b,
    const float* __restrict__ Whh_f, const float* __restrict__ Whh_b,
    unsigned* __restrict__ hpack, unsigned* __restrict__ hbf,
    unsigned* __restrict__ flags)
{
    int dir   = blockIdx.x;        // grid (2, NCHUNK): dir-major -> dir0 even XCDs
    int chunk = blockIdx.y;        // 0..15 (32 hidden units each)
    int tid = threadIdx.x;
    int wv = tid >> 6, l = tid & 63;
    int g  = wv & 3;               // gate
    int ks = wv >> 2;              // K-half (0/1)
    int lr = l & 15, lk = l >> 4;
    const float* zx  = dir ? zx_b  : zx_f;
    const float* Whh = dir ? Whh_b : Whh_f;
    unsigned* hb = hbf + (size_t)dir * (2*NB*NH);        // [slot][b][k] packed u32
    unsigned* flag = flags + (size_t)dir * (NCHUNK*8);   // dense [chunk][wave]

    // ---- preload Whh slice: gate g, units chunk*32+uh*16+lr, k-half ks ----
    short8v bwh[2][8], bwl[2][8];
    #pragma unroll
    for (int uh = 0; uh < 2; uh++) {
        const float* wrow = Whh + ((size_t)(g*NH + chunk*32 + uh*16 + lr))*NH + ks*256 + lk*8;
        #pragma unroll
        for (int kt = 0; kt < 8; kt++) {
            float u[8];
            *(float4*)&u[0] = *(const float4*)(wrow + kt*32);
            *(float4*)&u[4] = *(const float4*)(wrow + kt*32 + 4);
            short8v sh, sl;
            #pragma unroll
            for (int j = 0; j < 8; j++) {
                short hi = f2bf(u[j]);
                sh[j] = hi;
                sl[j] = f2bf(u[j] - bf2f(hi));
            }
            bwh[uh][kt] = sh; bwl[uh][kt] = sl;
        }
    }

    // swizzled h stage: [32][256] u64, col ^= (row&7)<<1 (64 KB)
    __shared__ unsigned long long hstage[32*256];
    __shared__ float zsh[2][4][32][36];      // stride 36: (4row+col)%32 -> 2-way
    float c0 = 0.f, c1 = 0.f;

    for (int t = 0; t < NS; t++) {
        int t_eff = dir ? (NS-1-t) : t;

        // ---- prefetch zx (independent of the flag) ----
        float pz[2][4];
        #pragma unroll
        for (int cc = 0; cc < 2; cc++) {
            int cell = tid + cc*512, b = cell >> 5, u = cell & 31;
            const float* zr = zx + ((size_t)(b*NS + t_eff))*NG4 + chunk*32 + u;
            #pragma unroll
            for (int g2 = 0; g2 < 4; g2++) pz[cc][g2] = zr[g2*NH];
        }

        if (t > 0) {
            // ---- poll all 128 per-wave flags (2 per lane via u64) ----
            {
                const unsigned long long* fp =
                    (const unsigned long long*)flag + l;
                unsigned tv = (unsigned)t;
                unsigned long long v;
                do { v = ld64_sc1(fp); }
                while (!__all(((unsigned)v >= tv) && ((unsigned)(v>>32) >= tv)));
                asm volatile("" ::: "memory");
            }
            // ---- burst stage: 16 coalesced u64 sc1 loads/thread -> swizzled LDS ----
            const unsigned long long* hp64 =
                (const unsigned long long*)(hb + ((t-1)&1)*(NB*NH));
            unsigned long long sv[16];
            #pragma unroll
            for (int i = 0; i < 16; i++) sv[i] = ld64_sc1(hp64 + i*512 + tid);
            #pragma unroll
            for (int i = 0; i < 16; i++) {
                int f = i*512 + tid, row = f >> 8, col = f & 255;
                hstage[row*256 + (col ^ ((row&7)<<1))] = sv[i];
            }
        }
        __syncthreads();   // barrier A: stage visible

        // ---- split-K MFMA: wave covers k in [ks*256, ks*256+256) ----
        f32x4 acc[2][2][3];
        #pragma unroll
        for (int bh = 0; bh < 2; bh++)
            #pragma unroll
            for (int uh = 0; uh < 2; uh++)
                #pragma unroll
                for (int q = 0; q < 3; q++) acc[bh][uh][q] = (f32x4){0.f,0.f,0.f,0.f};
        if (t > 0) {
            #pragma unroll
            for (int kt = 0; kt < 8; kt++) {
                short8v ah[2], al[2];
                #pragma unroll
                for (int bh = 0; bh < 2; bh++) {
                    int row = bh*16 + lr;
                    int base = ks*128 + kt*16 + lk*4;
                    int sw = (row&7)<<1;
                    const unsigned long long* p0 = &hstage[row*256 + ( base      ^ sw)];
                    const unsigned long long* p1 = &hstage[row*256 + ((base + 2) ^ sw)];
                    unsigned long long q0 = p0[0], q1 = p0[1], q2 = p1[0], q3 = p1[1];
                    unsigned w8[8];
                    w8[0]=(unsigned)q0; w8[1]=(unsigned)(q0>>32);
                    w8[2]=(unsigned)q1; w8[3]=(unsigned)(q1>>32);
                    w8[4]=(unsigned)q2; w8[5]=(unsigned)(q2>>32);
                    w8[6]=(unsigned)q3; w8[7]=(unsigned)(q3>>32);
                    unpack8(w8, ah[bh], al[bh]);
                }
                #pragma unroll
                for (int bh = 0; bh < 2; bh++)
                    #pragma unroll
                    for (int uh = 0; uh < 2; uh++) {
                        acc[bh][uh][0] = __builtin_amdgcn_mfma_f32_16x16x32_bf16(ah[bh], bwh[uh][kt], acc[bh][uh][0], 0, 0, 0);
                        acc[bh][uh][1] = __builtin_amdgcn_mfma_f32_16x16x32_bf16(al[bh], bwh[uh][kt], acc[bh][uh][1], 0, 0, 0);
                        acc[bh][uh][2] = __builtin_amdgcn_mfma_f32_16x16x32_bf16(ah[bh], bwl[uh][kt], acc[bh][uh][2], 0, 0, 0);
                    }
            }
        }
        // C layout: col=lane&15 -> unit uh*16+lr, row=(lane>>4)*4+j -> batch
        #pragma unroll
        for (int bh = 0; bh < 2; bh++)
            #pragma unroll
            for (int uh = 0; uh < 2; uh++)
                #pragma unroll
                for (int j = 0; j < 4; j++)
                    zsh[ks][g][bh*16 + lk*4 + j][uh*16 + lr] =
                        acc[bh][uh][0][j] + acc[bh][uh][1][j] + acc[bh][uh][2][j];
        __syncthreads();   // barrier B: zsh ready

        // ---- epilogue: 1024 cells / 512 threads (2 each) ----
        unsigned hq0 = 0, hq1 = 0;
        #pragma unroll
        for (int cc = 0; cc < 2; cc++) {
            int cell = tid + cc*512, b = cell >> 5, u = cell & 31;
            float zi = pz[cc][0] + zsh[0][0][b][u] + zsh[1][0][b][u];
            float zf = pz[cc][1] + zsh[0][1][b][u] + zsh[1][1][b][u];
            float zg = pz[cc][2] + zsh[0][2][b][u] + zsh[1][2][b][u];
            float zo = pz[cc][3] + zsh[0][3][b][u] + zsh[1][3][b][u];
            float cold = cc ? c1 : c0;
            float cn = sigmoidf_(zf)*cold + sigmoidf_(zi)*tanhf(zg);
            float hn = sigmoidf_(zo)*tanhf(cn);
            unsigned pk = packbf3(hn);
            if (cc) { c1 = cn; hq1 = pk; } else { c0 = cn; hq0 = pk; }
            st_sc1(&hb[(size_t)(t&1)*(NB*NH) + b*NH + chunk*32 + u], pk);
        }
        // per-wave release: own stores acked at coherence point, then own flag
        asm volatile("s_waitcnt vmcnt(0)" ::: "memory");
        if (l == 0) st_sc1(&flag[chunk*8 + wv], (unsigned)(t+1));
        // packed h for downstream GEMMs (off critical path)
        #pragma unroll
        for (int cc = 0; cc < 2; cc++) {
            int cell = tid + cc*512, b = cell >> 5, u = cell & 31;
            hpack[((size_t)(b*NS + t_eff))*NIN1 + dir*NH + chunk*32 + u] = cc ? hq1 : hq0;
        }
    }
}

// ---------------- emissions: em = hid1 @ lin2W^T + b2 ----------------
__global__ __launch_bounds__(256) void k_lin2(const float* __restrict__ hid,
    const float* __restrict__ W2, const float* __restrict__ b2, float* __restrict__ em)
{
    int flat = blockIdx.x*256 + threadIdx.x;
    if (flat >= NBS*NT) return;
    int m = flat / NT, j = flat % NT;
    const float* hr = hid + (size_t)m*NHID;
    const float* wr = W2 + j*NHID;
    float acc = b2[j];
    #pragma unroll 8
    for (int k = 0; k < NHID; k += 4) {
        float4 h4 = *(const float4*)(hr+k);
        float4 w4 = *(const float4*)(wr+k);
        acc += h4.x*w4.x + h4.y*w4.y + h4.z*w4.z + h4.w*w4.w;
    }
    em[flat] = acc;
}

// ---------------- viterbi decode (one wave per batch item) ----------------
__global__ __launch_bounds__(64) void k_viterbi(const float* __restrict__ em,
    const float* __restrict__ start, const float* __restrict__ endv,
    const float* __restrict__ trans, float* __restrict__ dec)
{
    __shared__ float sc[NT];
    __shared__ float tr[NT][NT];
    __shared__ unsigned char hist[NS][NT];
    int b = blockIdx.x, tid = threadIdx.x;
    for (int i = tid; i < NT*NT; i += 64) tr[i/NT][i%NT] = trans[i];
    if (tid < NT) sc[tid] = start[tid] + em[((size_t)b*NS)*NT + tid];
    __syncthreads();
    for (int t = 1; t < NS; t++) {
        float best = -1e30f; int bi = 0;
        if (tid < NT) {
            for (int i = 0; i < NT; i++) {
                float v = sc[i] + tr[i][tid];
                if (v > best) { best = v; bi = i; }
            }
            hist[t][tid] = (unsigned char)bi;
            best += em[((size_t)b*NS + t)*NT + tid];
        }
        __syncthreads();
        if (tid < NT) sc[tid] = best;
        __syncthreads();
    }
    if (tid == 0) {
        float bv = sc[0] + endv[0]; int tag = 0;
        for (int j = 1; j < NT; j++) { float v = sc[j] + endv[j]; if (v > bv) { bv = v; tag = j; } }
        dec[b*NS + NS-1] = (float)tag;
        for (int t = NS-1; t >= 1; t--) { tag = hist[t][tag]; dec[b*NS + t-1] = (float)tag; }
    }
}

// ---------------- CRF NLL (mask is all ones) ----------------
__global__ __launch_bounds__(64) void k_nll(const float* __restrict__ em,
    const int* __restrict__ tags, const float* __restrict__ start,
    const float* __restrict__ endv, const float* __restrict__ trans,
    float* __restrict__ partial)
{
    __shared__ float sc[NT];
    __shared__ float tr[NT][NT];
    int b = blockIdx.x, tid = threadIdx.x;
    for (int i = tid; i < NT*NT; i += 64) tr[i/NT][i%NT] = trans[i];
    if (tid < NT) sc[tid] = start[tid] + em[((size_t)b*NS)*NT + tid];
    __syncthreads();
    for (int t = 1; t < NS; t++) {
        float nv = 0.f;
        if (tid < NT) {
            float m = -1e30f;
            for (int i = 0; i < NT; i++) m = fmaxf(m, sc[i] + tr[i][tid]);
            float s = 0.f;
            for (int i = 0; i < NT; i++) s += expf(sc[i] + tr[i][tid] - m);
            nv = m + logf(s) + em[((size_t)b*NS + t)*NT + tid];
        }
        __syncthreads();
        if (tid < NT) sc[tid] = nv;
        __syncthreads();
    }
    if (tid == 0) {
        float m = -1e30f;
        for (int j = 0; j < NT; j++) m = fmaxf(m, sc[j] + endv[j]);
        float s = 0.f;
        for (int j = 0; j < NT; j++) s += expf(sc[j] + endv[j] - m);
        float logZ = m + logf(s);
        const int* tg = tags + b*NS;
        float num = start[tg[0]] + em[((size_t)b*NS)*NT + tg[0]];
        for (int t = 1; t < NS; t++)
            num += tr[tg[t-1]][tg[t]] + em[((size_t)b*NS + t)*NT + tg[t]];
        num += endv[tg[NS-1]];
        partial[b] = -(num - logZ);
    }
}

__global__ void k_loss_final(const float* __restrict__ partial, float* __restrict__ loss)
{
    if (threadIdx.x == 0 && blockIdx.x == 0) {
        float s = 0.f;
        for (int b = 0; b < NB; b++) s += partial[b];
        *loss = s / (float)(NB*NS);
    }
}

extern "C" void kernel_launch(void* const* d_in, const int* in_sizes, int n_in,
                              void* d_out, int out_size, void* d_ws, size_t ws_size,
                              hipStream_t stream)
{
    const int*   x_word = (const int*)d_in[0];
    const float* x_pos  = (const float*)d_in[1];
    const int*   x_char = (const int*)d_in[2];
    const float* x_enr  = (const float*)d_in[3];
    const int*   y_word = (const int*)d_in[5];
    const float* wembW  = (const float*)d_in[6];
    const float* cembW  = (const float*)d_in[7];
    const float* cnnW   = (const float*)d_in[8];
    const float* cnnb   = (const float*)d_in[9];
    const float* lin1W  = (const float*)d_in[10];
    const float* lin1b  = (const float*)d_in[11];
    const float* lin2W  = (const float*)d_in[12];
    const float* lin2b  = (const float*)d_in[13];
    const float* crf_s  = (const float*)d_in[14];
    const float* crf_e  = (const float*)d_in[15];
    const float* crf_tr = (const float*)d_in[16];
    const float* l0f_Wih = (const float*)d_in[17];
    const float* l0f_Whh = (const float*)d_in[18];
    const float* l0f_b   = (const float*)d_in[19];
    const float* l0b_Wih = (const float*)d_in[20];
    const float* l0b_Whh = (const float*)d_in[21];
    const float* l0b_b   = (const float*)d_in[22];
    const float* l1f_Wih = (const float*)d_in[23];
    const float* l1f_Whh = (const float*)d_in[24];
    const float* l1f_b   = (const float*)d_in[25];
    const float* l1b_Wih = (const float*)d_in[26];
    const float* l1b_Whh = (const float*)d_in[27];
    const float* l1b_b   = (const float*)d_in[28];

    unsigned* ws = (unsigned*)d_ws;
    size_t off = 0;
    unsigned* xwp  = ws + off; off += (size_t)NBS*NIN0P;
    unsigned* w0fp = ws + off; off += (size_t)NG4*NIN0P;
    unsigned* w0bp = ws + off; off += (size_t)NG4*NIN0P;
    unsigned* w1fp = ws + off; off += (size_t)NG4*NIN1;
    unsigned* w1bp = ws + off; off += (size_t)NG4*NIN1;
    unsigned* wl1p = ws + off; off += (size_t)NHID*NIN1;
    float*    zxf  = (float*)(ws + off); off += (size_t)NBS*NG4;
    float*    zxb  = (float*)(ws + off); off += (size_t)NBS*NG4;
    unsigned* h0p  = ws + off; off += (size_t)NBS*NIN1;
    unsigned* h1p  = ws + off; off += (size_t)NBS*NIN1;
    float*    hid1 = (float*)(ws + off); off += (size_t)NBS*NHID;
    float*    partial = (float*)(ws + off); off += 64;
    unsigned* hbf  = ws + off; off += (size_t)2*2*NB*NH;
    unsigned* flags= ws + off; off += (size_t)2*NCHUNK*8;

    float* em_out   = (float*)d_out;
    float* dec_out  = em_out + (size_t)NBS*NT;
    float* loss_out = dec_out + NBS;

    // 1. pack weights
    k_pack_w<<<(NG4*NIN0P+255)/256, 256, 0, stream>>>(l0f_Wih, w0fp, NG4, NIN0, NIN0P);
    k_pack_w<<<(NG4*NIN0P+255)/256, 256, 0, stream>>>(l0b_Wih, w0bp, NG4, NIN0, NIN0P);
    k_pack_w<<<(NG4*NIN1+255)/256, 256, 0, stream>>>(l1f_Wih, w1fp, NG4, NIN1, NIN1);
    k_pack_w<<<(NG4*NIN1+255)/256, 256, 0, stream>>>(l1b_Wih, w1bp, NG4, NIN1, NIN1);
    k_pack_w<<<(NHID*NIN1+255)/256, 256, 0, stream>>>(lin1W, wl1p, NHID, NIN1, NIN1);
    // 2. features (packed)
    k_features<<<NBS, 128, 0, stream>>>(x_word, x_pos, x_char, x_enr, wembW, cembW, cnnW, cnnb, xwp);
    // 3. layer-0 input projections
    k_gemm_bf3<<<dim3(NBS/128, NG4/128), 256, 0, stream>>>(xwp, w0fp, l0f_b, zxf, NBS, NG4, NIN0P);
    k_gemm_bf3<<<dim3(NBS/128, NG4/128), 256, 0, stream>>>(xwp, w0bp, l0b_b, zxb, NBS, NG4, NIN0P);
    // 4. layer-0 recurrence
    hipMemsetAsync(flags, 0, (size_t)2*NCHUNK*8*sizeof(unsigned), stream);
    k_lstm_layer<<<dim3(2, NCHUNK), 512, 0, stream>>>(zxf, zxb, l0f_Whh, l0b_Whh, h0p, hbf, flags);
    // 5. layer-1 input projections
    k_gemm_bf3<<<dim3(NBS/128, NG4/128), 256, 0, stream>>>(h0p, w1fp, l1f_b, zxf, NBS, NG4, NIN1);
    k_gemm_bf3<<<dim3(NBS/128, NG4/128), 256, 0, stream>>>(h0p, w1bp, l1b_b, zxb, NBS, NG4, NIN1);
    // 6. layer-1 recurrence
    hipMemsetAsync(flags, 0, (size_t)2*NCHUNK*8*sizeof(unsigned), stream);
    k_lstm_layer<<<dim3(2, NCHUNK), 512, 0, stream>>>(zxf, zxb, l1f_Whh, l1b_Whh, h1p, hbf, flags);
    // 7. head
    k_gemm_bf3<<<dim3(NBS/128, NHID/128), 256, 0, stream>>>(h1p, wl1p, lin1b, hid1, NBS, NHID, NIN1);
    k_lin2<<<(NBS*NT+255)/256, 256, 0, stream>>>(hid1, lin2W, lin2b, em_out);
    // 8. CRF
    k_viterbi<<<NB, 64, 0, stream>>>(em_out, crf_s, crf_e, crf_tr, dec_out);
    k_nll<<<NB, 64, 0, stream>>>(em_out, y_word, crf_s, crf_e, crf_tr, partial);
    k_loss_final<<<1, 64, 0, stream>>>(partial, loss_out);
}

// Round 11
// 5945.048 us; speedup vs baseline: 1.0807x; 1.0807x over previous
//
#include <hip/hip_runtime.h>
#include <hip/hip_bf16.h>
#include <math.h>

// ---- problem dims ----
constexpr int NB   = 32;
constexpr int NS   = 256;
constexpr int NLC  = 16;
constexpr int NWD  = 256;
constexpr int NCD  = 124;
constexpr int NCO  = 32;
constexpr int NPOS = 36;
constexpr int NENR = 7;
constexpr int NH   = 512;
constexpr int NT   = 18;
constexpr int NIN0 = 331;
constexpr int NIN0P= 352;    // padded to x32 for BK=32
constexpr int NIN1 = 1024;
constexpr int NBS  = NB*NS;  // 8192
constexpr int NG4  = 4*NH;   // 2048
constexpr int NHID = 128;
constexpr int NCHUNK = 16;   // unit-chunks per dir (32 units each)

typedef __attribute__((ext_vector_type(8))) short short8v;
typedef __attribute__((ext_vector_type(4))) float f32x4;

__device__ __forceinline__ float sigmoidf_(float x){ return 1.0f/(1.0f+expf(-x)); }
__device__ __forceinline__ short f2bf(float f) {
    union { __hip_bfloat16 h; short s; } u;
    u.h = __float2bfloat16(f);
    return u.s;
}
__device__ __forceinline__ float bf2f(short s) {
    union { unsigned u; float f; } v;
    v.u = ((unsigned)(unsigned short)s) << 16;
    return v.f;
}
__device__ __forceinline__ unsigned packbf3(float v) {
    short hi = f2bf(v);
    short lo = f2bf(v - bf2f(hi));
    return ((unsigned)(unsigned short)hi << 16) | (unsigned short)lo;
}
// 8 packed u32 (elems k..k+7) -> hi/lo bf16 fragments
__device__ __forceinline__ void unpack8(const unsigned* w, short8v& hi, short8v& lo) {
    union U { short8v s; unsigned u[4]; } H, L;
    #pragma unroll
    for (int i = 0; i < 4; i++) {
        H.u[i] = (w[2*i+1] & 0xFFFF0000u) | (w[2*i] >> 16);
        L.u[i] = (w[2*i+1] << 16) | (w[2*i] & 0xFFFFu);
    }
    hi = H.s; lo = L.s;
}
// relaxed agent-scope ops (sc1 path, no cache maintenance) — proven in r6
__device__ __forceinline__ unsigned ld_sc1(const unsigned* p) {
    return __hip_atomic_load(p, __ATOMIC_RELAXED, __HIP_MEMORY_SCOPE_AGENT);
}
__device__ __forceinline__ void st_sc1(unsigned* p, unsigned v) {
    __hip_atomic_store(p, v, __ATOMIC_RELAXED, __HIP_MEMORY_SCOPE_AGENT);
}

// ---------------- features: word embed + char CNN + concat + relu -> packed u32 ----
__global__ __launch_bounds__(128) void k_features(const int* __restrict__ x_word,
    const float* __restrict__ x_pos, const int* __restrict__ x_char,
    const float* __restrict__ x_enr, const float* __restrict__ wembW,
    const float* __restrict__ cembW, const float* __restrict__ cnnW,
    const float* __restrict__ cnnb, unsigned* __restrict__ xout)
{
    __shared__ float ce[NLC][NCD];
    __shared__ float cv[NCO][13];
    __shared__ float cpool[NCO];
    int n = blockIdx.x;
    int tid = threadIdx.x;
    for (int i = tid; i < NLC*NCD; i += 128) {
        int l = i / NCD, c = i % NCD;
        ce[l][c] = cembW[x_char[n*NLC + l]*NCD + c];
    }
    __syncthreads();
    for (int p = tid; p < NCO*12; p += 128) {
        int o = p & 31, t = p >> 5;
        const float* wr = cnnW + o*NCD*5;
        float acc = 0.f;
        for (int c = 0; c < NCD; c++) {
            #pragma unroll
            for (int k = 0; k < 5; k++) acc += ce[t+k][c] * wr[c*5+k];
        }
        cv[o][t] = acc;
    }
    __syncthreads();
    if (tid < NCO) {
        float m = cv[tid][0];
        #pragma unroll
        for (int t = 1; t < 12; t++) m = fmaxf(m, cv[tid][t]);
        cpool[tid] = m + cnnb[tid];
    }
    __syncthreads();
    int widx = x_word[n];
    unsigned* xr = xout + (size_t)n * NIN0P;
    for (int j = tid; j < NIN0P; j += 128) {
        float v;
        if (j < NWD)            v = wembW[(size_t)widx*NWD + j];
        else if (j < NWD+NPOS)  v = x_pos[n*NPOS + (j-NWD)];
        else if (j < NWD+NPOS+NCO) v = cpool[j-(NWD+NPOS)];
        else if (j < NIN0)      v = x_enr[n*NENR + (j-(NWD+NPOS+NCO))];
        else                    v = 0.f;   // K pad
        xr[j] = packbf3(fmaxf(v, 0.f));
    }
}

// ---------------- pack f32 weight [N][Ksrc] -> packed u32 [N][Kdst] (zero pad) ----
__global__ void k_pack_w(const float* __restrict__ W, unsigned* __restrict__ out,
                         int N, int Ksrc, int Kdst)
{
    int idx = blockIdx.x*256 + threadIdx.x;
    if (idx >= N*Kdst) return;
    int n = idx / Kdst, k = idx % Kdst;
    float v = (k < Ksrc) ? W[(size_t)n*Ksrc + k] : 0.f;
    out[idx] = packbf3(v);
}

// ---------------- bf16x3 MFMA GEMM: C[M,N] = A@W^T + bias ----------------
constexpr int TBK = 32;
constexpr int LSTR = 36;
__global__ __launch_bounds__(256, 2) void k_gemm_bf3(
    const unsigned* __restrict__ A, const unsigned* __restrict__ W,
    const float* __restrict__ bias, float* __restrict__ C,
    int M, int N, int K)
{
    __shared__ unsigned Asl[128*LSTR];
    __shared__ unsigned Bsl[128*LSTR];
    int bm = blockIdx.x*128, bn = blockIdx.y*128;
    int tid = threadIdx.x;
    int l = tid & 63, wv = tid >> 6;
    int wm = wv >> 1, wn = wv & 1;
    int lr = l & 15, lk = l >> 4;

    f32x4 acc[4][4];
    #pragma unroll
    for (int i = 0; i < 4; i++)
        #pragma unroll
        for (int j = 0; j < 4; j++) acc[i][j] = (f32x4){0.f,0.f,0.f,0.f};

    uint4 ra[4], rb[4];
    int KT = K / TBK;
    #pragma unroll
    for (int i = 0; i < 4; i++) {
        int idx = i*256 + tid, row = idx >> 3, c4 = (idx & 7)*4;
        ra[i] = *(const uint4*)(A + (size_t)(bm+row)*K + c4);
        rb[i] = *(const uint4*)(W + (size_t)(bn+row)*K + c4);
    }
    for (int kt = 0; kt < KT; kt++) {
        #pragma unroll
        for (int i = 0; i < 4; i++) {
            int idx = i*256 + tid, row = idx >> 3, c4 = (idx & 7)*4;
            *(uint4*)&Asl[row*LSTR + c4] = ra[i];
            *(uint4*)&Bsl[row*LSTR + c4] = rb[i];
        }
        __syncthreads();
        if (kt+1 < KT) {
            #pragma unroll
            for (int i = 0; i < 4; i++) {
                int idx = i*256 + tid, row = idx >> 3, c4 = (idx & 7)*4;
                ra[i] = *(const uint4*)(A + (size_t)(bm+row)*K + (kt+1)*TBK + c4);
                rb[i] = *(const uint4*)(W + (size_t)(bn+row)*K + (kt+1)*TBK + c4);
            }
        }
        short8v Ah[4], Al_[4], Bh[4], Bl[4];
        #pragma unroll
        for (int f = 0; f < 4; f++) {
            unsigned w8[8];
            int rowA = wm*64 + f*16 + lr;
            *(uint4*)&w8[0] = *(const uint4*)&Asl[rowA*LSTR + lk*8];
            *(uint4*)&w8[4] = *(const uint4*)&Asl[rowA*LSTR + lk*8 + 4];
            unpack8(w8, Ah[f], Al_[f]);
            int rowB = wn*64 + f*16 + lr;
            *(uint4*)&w8[0] = *(const uint4*)&Bsl[rowB*LSTR + lk*8];
            *(uint4*)&w8[4] = *(const uint4*)&Bsl[rowB*LSTR + lk*8 + 4];
            unpack8(w8, Bh[f], Bl[f]);
        }
        #pragma unroll
        for (int i = 0; i < 4; i++)
            #pragma unroll
            for (int j = 0; j < 4; j++) {
                acc[i][j] = __builtin_amdgcn_mfma_f32_16x16x32_bf16(Ah[i],  Bh[j], acc[i][j], 0, 0, 0);
                acc[i][j] = __builtin_amdgcn_mfma_f32_16x16x32_bf16(Al_[i], Bh[j], acc[i][j], 0, 0, 0);
                acc[i][j] = __builtin_amdgcn_mfma_f32_16x16x32_bf16(Ah[i],  Bl[j], acc[i][j], 0, 0, 0);
            }
        __syncthreads();
    }
    #pragma unroll
    for (int i = 0; i < 4; i++) {
        int m0 = bm + wm*64 + i*16 + lk*4;
        #pragma unroll
        for (int j = 0; j < 4; j++) {
            int n0 = bn + wn*64 + j*16 + lr;
            float bv = bias[n0];
            #pragma unroll
            for (int q = 0; q < 4; q++)
                C[(size_t)(m0+q)*N + n0] = acc[i][j][q] + bv;
        }
    }
}

// ---------------- persistent LSTM layer: 16 chunks x 2 dirs, 512 thr ----------
// r6 structure (best measured) with FLAG-FREE tagged-data exchange:
// each hb cell's low 2 bits = step tag (t%3)+1 (stolen from bf16-lo mantissa,
// ~2^-15 rel noise). Consumers load cells and retry until tags match — the
// tag check IS the sync. Producer: fire-and-forget sc1 stores; no vmcnt(0),
// no flag, no drain barrier. 2-slot ring + mod-3 tag + per-launch memset
// eliminates slot aliasing (safety: block at t+2 overwrites slot t&1 only
// after staging ALL t+1 tags, which certifies all blocks finished t+1 reads
// of slot t&1). Two barriers per step.
__global__ __launch_bounds__(512, 2) void k_lstm_layer(
    const float* __restrict__ zx_f, const float* __restrict__ zx_b,
    const float* __restrict__ Whh_f, const float* __restrict__ Whh_b,
    unsigned* __restrict__ hpack, unsigned* __restrict__ hbf)
{
    int chunk = blockIdx.x;        // 0..15 (32 hidden units each)
    int dir   = blockIdx.y;
    int tid = threadIdx.x;
    int wv = tid >> 6, l = tid & 63;
    int g  = wv & 3;               // gate
    int ks = wv >> 2;              // K-half (0/1)
    int lr = l & 15, lk = l >> 4;
    const float* zx  = dir ? zx_b  : zx_f;
    const float* Whh = dir ? Whh_b : Whh_f;
    unsigned* hb = hbf + (size_t)dir * (2*NB*NH);     // [slot][b][k] tagged u32

    // ---- preload Whh slice: gate g, units chunk*32+uh*16+lr, k-half ks ----
    short8v bwh[2][8], bwl[2][8];
    #pragma unroll
    for (int uh = 0; uh < 2; uh++) {
        const float* wrow = Whh + ((size_t)(g*NH + chunk*32 + uh*16 + lr))*NH + ks*256 + lk*8;
        #pragma unroll
        for (int kt = 0; kt < 8; kt++) {
            float u[8];
            *(float4*)&u[0] = *(const float4*)(wrow + kt*32);
            *(float4*)&u[4] = *(const float4*)(wrow + kt*32 + 4);
            short8v sh, sl;
            #pragma unroll
            for (int j = 0; j < 8; j++) {
                short hi = f2bf(u[j]);
                sh[j] = hi;
                sl[j] = f2bf(u[j] - bf2f(hi));
            }
            bwh[uh][kt] = sh; bwl[uh][kt] = sl;
        }
    }

    __shared__ unsigned hstage[32*516];      // h_prev staged per block (r6 layout)
    __shared__ float zsh[2][4][32][33];      // [ks][gate][batch][unit] partials
    float c0 = 0.f, c1 = 0.f;

    for (int t = 0; t < NS; t++) {
        int t_eff = dir ? (NS-1-t) : t;

        // ---- prefetch zx into regs (L2-warm, independent of exchange) ----
        float pz[2][4];
        #pragma unroll
        for (int cc = 0; cc < 2; cc++) {
            int cell = tid + cc*512, b = cell >> 5, u = cell & 31;
            const float* zr = zx + ((size_t)(b*NS + t_eff))*NG4 + chunk*32 + u;
            #pragma unroll
            for (int g2 = 0; g2 < 4; g2++) pz[cc][g2] = zr[g2*NH];
        }

        if (t > 0) {
            // ---- tagged burst stage: 32 coalesced sc1 loads/thread, retry stale ----
            const unsigned exptag = (unsigned)((t-1)%3) + 1;
            const unsigned* hp = hb + ((t-1)&1)*(NB*NH);
            unsigned sv[32];
            unsigned okm = 0u;
            #pragma unroll
            for (int i = 0; i < 32; i++) sv[i] = ld_sc1(hp + i*512 + tid);
            for (;;) {
                #pragma unroll
                for (int i = 0; i < 32; i++)
                    if (!((okm >> i) & 1u) && (sv[i] & 3u) == exptag) okm |= (1u << i);
                if (okm == 0xFFFFFFFFu) break;
                #pragma unroll
                for (int i = 0; i < 32; i++)
                    if (!((okm >> i) & 1u)) sv[i] = ld_sc1(hp + i*512 + tid);
            }
            #pragma unroll
            for (int i = 0; i < 32; i++) hstage[i*516 + tid] = sv[i];
        }
        __syncthreads();   // barrier A: stage visible

        // ---- split-K MFMA: wave covers k in [ks*256, ks*256+256) ----
        f32x4 acc[2][2][3];
        #pragma unroll
        for (int bh = 0; bh < 2; bh++)
            #pragma unroll
            for (int uh = 0; uh < 2; uh++)
                #pragma unroll
                for (int q = 0; q < 3; q++) acc[bh][uh][q] = (f32x4){0.f,0.f,0.f,0.f};
        if (t > 0) {
            #pragma unroll
            for (int kt = 0; kt < 8; kt++) {
                short8v ah[2], al[2];
                #pragma unroll
                for (int bh = 0; bh < 2; bh++) {
                    unsigned w8[8];
                    const unsigned* sp = hstage + (bh*16+lr)*516 + ks*256 + kt*32 + lk*8;
                    *(uint4*)&w8[0] = *(const uint4*)sp;
                    *(uint4*)&w8[4] = *(const uint4*)(sp+4);
                    unpack8(w8, ah[bh], al[bh]);
                }
                #pragma unroll
                for (int bh = 0; bh < 2; bh++)
                    #pragma unroll
                    for (int uh = 0; uh < 2; uh++) {
                        acc[bh][uh][0] = __builtin_amdgcn_mfma_f32_16x16x32_bf16(ah[bh], bwh[uh][kt], acc[bh][uh][0], 0, 0, 0);
                        acc[bh][uh][1] = __builtin_amdgcn_mfma_f32_16x16x32_bf16(al[bh], bwh[uh][kt], acc[bh][uh][1], 0, 0, 0);
                        acc[bh][uh][2] = __builtin_amdgcn_mfma_f32_16x16x32_bf16(ah[bh], bwl[uh][kt], acc[bh][uh][2], 0, 0, 0);
                    }
            }
        }
        // C layout: col=lane&15 -> unit uh*16+lr, row=(lane>>4)*4+j -> batch
        #pragma unroll
        for (int bh = 0; bh < 2; bh++)
            #pragma unroll
            for (int uh = 0; uh < 2; uh++)
                #pragma unroll
                for (int j = 0; j < 4; j++)
                    zsh[ks][g][bh*16 + lk*4 + j][uh*16 + lr] =
                        acc[bh][uh][0][j] + acc[bh][uh][1][j] + acc[bh][uh][2][j];
        __syncthreads();   // barrier B: zsh ready

        // ---- epilogue: 1024 cells / 512 threads; tagged fire-and-forget stores ----
        const unsigned wtag = (unsigned)(t%3) + 1;
        unsigned hq0 = 0, hq1 = 0;
        #pragma unroll
        for (int cc = 0; cc < 2; cc++) {
            int cell = tid + cc*512, b = cell >> 5, u = cell & 31;
            float zi = pz[cc][0] + zsh[0][0][b][u] + zsh[1][0][b][u];
            float zf = pz[cc][1] + zsh[0][1][b][u] + zsh[1][1][b][u];
            float zg = pz[cc][2] + zsh[0][2][b][u] + zsh[1][2][b][u];
            float zo = pz[cc][3] + zsh[0][3][b][u] + zsh[1][3][b][u];
            float cold = cc ? c1 : c0;
            float cn = sigmoidf_(zf)*cold + sigmoidf_(zi)*tanhf(zg);
            float hn = sigmoidf_(zo)*tanhf(cn);
            unsigned pk = (packbf3(hn) & ~3u) | wtag;
            if (cc) { c1 = cn; hq1 = pk; } else { c0 = cn; hq0 = pk; }
            st_sc1(&hb[(size_t)(t&1)*(NB*NH) + b*NH + chunk*32 + u], pk);
        }
        // packed h for downstream GEMMs (tag bits = 2^-15 noise, harmless)
        #pragma unroll
        for (int cc = 0; cc < 2; cc++) {
            int cell = tid + cc*512, b = cell >> 5, u = cell & 31;
            hpack[((size_t)(b*NS + t_eff))*NIN1 + dir*NH + chunk*32 + u] = cc ? hq1 : hq0;
        }
    }
}

// ---------------- emissions: em = hid1 @ lin2W^T + b2 ----------------
__global__ __launch_bounds__(256) void k_lin2(const float* __restrict__ hid,
    const float* __restrict__ W2, const float* __restrict__ b2, float* __restrict__ em)
{
    int flat = blockIdx.x*256 + threadIdx.x;
    if (flat >= NBS*NT) return;
    int m = flat / NT, j = flat % NT;
    const float* hr = hid + (size_t)m*NHID;
    const float* wr = W2 + j*NHID;
    float acc = b2[j];
    #pragma unroll 8
    for (int k = 0; k < NHID; k += 4) {
        float4 h4 = *(const float4*)(hr+k);
        float4 w4 = *(const float4*)(wr+k);
        acc += h4.x*w4.x + h4.y*w4.y + h4.z*w4.z + h4.w*w4.w;
    }
    em[flat] = acc;
}

// ---------------- viterbi decode (one wave per batch item) ----------------
__global__ __launch_bounds__(64) void k_viterbi(const float* __restrict__ em,
    const float* __restrict__ start, const float* __restrict__ endv,
    const float* __restrict__ trans, float* __restrict__ dec)
{
    __shared__ float sc[NT];
    __shared__ float tr[NT][NT];
    __shared__ unsigned char hist[NS][NT];
    int b = blockIdx.x, tid = threadIdx.x;
    for (int i = tid; i < NT*NT; i += 64) tr[i/NT][i%NT] = trans[i];
    if (tid < NT) sc[tid] = start[tid] + em[((size_t)b*NS)*NT + tid];
    __syncthreads();
    for (int t = 1; t < NS; t++) {
        float best = -1e30f; int bi = 0;
        if (tid < NT) {
            for (int i = 0; i < NT; i++) {
                float v = sc[i] + tr[i][tid];
                if (v > best) { best = v; bi = i; }
            }
            hist[t][tid] = (unsigned char)bi;
            best += em[((size_t)b*NS + t)*NT + tid];
        }
        __syncthreads();
        if (tid < NT) sc[tid] = best;
        __syncthreads();
    }
    if (tid == 0) {
        float bv = sc[0] + endv[0]; int tag = 0;
        for (int j = 1; j < NT; j++) { float v = sc[j] + endv[j]; if (v > bv) { bv = v; tag = j; } }
        dec[b*NS + NS-1] = (float)tag;
        for (int t = NS-1; t >= 1; t--) { tag = hist[t][tag]; dec[b*NS + t-1] = (float)tag; }
    }
}

// ---------------- CRF NLL (mask is all ones) ----------------
__global__ __launch_bounds__(64) void k_nll(const float* __restrict__ em,
    const int* __restrict__ tags, const float* __restrict__ start,
    const float* __restrict__ endv, const float* __restrict__ trans,
    float* __restrict__ partial)
{
    __shared__ float sc[NT];
    __shared__ float tr[NT][NT];
    int b = blockIdx.x, tid = threadIdx.x;
    for (int i = tid; i < NT*NT; i += 64) tr[i/NT][i%NT] = trans[i];
    if (tid < NT) sc[tid] = start[tid] + em[((size_t)b*NS)*NT + tid];
    __syncthreads();
    for (int t = 1; t < NS; t++) {
        float nv = 0.f;
        if (tid < NT) {
            float m = -1e30f;
            for (int i = 0; i < NT; i++) m = fmaxf(m, sc[i] + tr[i][tid]);
            float s = 0.f;
            for (int i = 0; i < NT; i++) s += expf(sc[i] + tr[i][tid] - m);
            nv = m + logf(s) + em[((size_t)b*NS + t)*NT + tid];
        }
        __syncthreads();
        if (tid < NT) sc[tid] = nv;
        __syncthreads();
    }
    if (tid == 0) {
        float m = -1e30f;
        for (int j = 0; j < NT; j++) m = fmaxf(m, sc[j] + endv[j]);
        float s = 0.f;
        for (int j = 0; j < NT; j++) s += expf(sc[j] + endv[j] - m);
        float logZ = m + logf(s);
        const int* tg = tags + b*NS;
        float num = start[tg[0]] + em[((size_t)b*NS)*NT + tg[0]];
        for (int t = 1; t < NS; t++)
            num += tr[tg[t-1]][tg[t]] + em[((size_t)b*NS + t)*NT + tg[t]];
        num += endv[tg[NS-1]];
        partial[b] = -(num - logZ);
    }
}

__global__ void k_loss_final(const float* __restrict__ partial, float* __restrict__ loss)
{
    if (threadIdx.x == 0 && blockIdx.x == 0) {
        float s = 0.f;
        for (int b = 0; b < NB; b++) s += partial[b];
        *loss = s / (float)(NB*NS);
    }
}

extern "C" void kernel_launch(void* const* d_in, const int* in_sizes, int n_in,
                              void* d_out, int out_size, void* d_ws, size_t ws_size,
                              hipStream_t stream)
{
    const int*   x_word = (const int*)d_in[0];
    const float* x_pos  = (const float*)d_in[1];
    const int*   x_char = (const int*)d_in[2];
    const float* x_enr  = (const float*)d_in[3];
    const int*   y_word = (const int*)d_in[5];
    const float* wembW  = (const float*)d_in[6];
    const float* cembW  = (const float*)d_in[7];
    const float* cnnW   = (const float*)d_in[8];
    const float* cnnb   = (const float*)d_in[9];
    const float* lin1W  = (const float*)d_in[10];
    const float* lin1b  = (const float*)d_in[11];
    const float* lin2W  = (const float*)d_in[12];
    const float* lin2b  = (const float*)d_in[13];
    const float* crf_s  = (const float*)d_in[14];
    const float* crf_e  = (const float*)d_in[15];
    const float* crf_tr = (const float*)d_in[16];
    const float* l0f_Wih = (const float*)d_in[17];
    const float* l0f_Whh = (const float*)d_in[18];
    const float* l0f_b   = (const float*)d_in[19];
    const float* l0b_Wih = (const float*)d_in[20];
    const float* l0b_Whh = (const float*)d_in[21];
    const float* l0b_b   = (const float*)d_in[22];
    const float* l1f_Wih = (const float*)d_in[23];
    const float* l1f_Whh = (const float*)d_in[24];
    const float* l1f_b   = (const float*)d_in[25];
    const float* l1b_Wih = (const float*)d_in[26];
    const float* l1b_Whh = (const float*)d_in[27];
    const float* l1b_b   = (const float*)d_in[28];

    unsigned* ws = (unsigned*)d_ws;
    size_t off = 0;
    unsigned* xwp  = ws + off; off += (size_t)NBS*NIN0P;
    unsigned* w0fp = ws + off; off += (size_t)NG4*NIN0P;
    unsigned* w0bp = ws + off; off += (size_t)NG4*NIN0P;
    unsigned* w1fp = ws + off; off += (size_t)NG4*NIN1;
    unsigned* w1bp = ws + off; off += (size_t)NG4*NIN1;
    unsigned* wl1p = ws + off; off += (size_t)NHID*NIN1;
    float*    zxf  = (float*)(ws + off); off += (size_t)NBS*NG4;
    float*    zxb  = (float*)(ws + off); off += (size_t)NBS*NG4;
    unsigned* h0p  = ws + off; off += (size_t)NBS*NIN1;
    unsigned* h1p  = ws + off; off += (size_t)NBS*NIN1;
    float*    hid1 = (float*)(ws + off); off += (size_t)NBS*NHID;
    float*    partial = (float*)(ws + off); off += 64;
    unsigned* hbf  = ws + off; off += (size_t)2*2*NB*NH;   // tagged h ring

    float* em_out   = (float*)d_out;
    float* dec_out  = em_out + (size_t)NBS*NT;
    float* loss_out = dec_out + NBS;

    // 1. pack weights
    k_pack_w<<<(NG4*NIN0P+255)/256, 256, 0, stream>>>(l0f_Wih, w0fp, NG4, NIN0, NIN0P);
    k_pack_w<<<(NG4*NIN0P+255)/256, 256, 0, stream>>>(l0b_Wih, w0bp, NG4, NIN0, NIN0P);
    k_pack_w<<<(NG4*NIN1+255)/256, 256, 0, stream>>>(l1f_Wih, w1fp, NG4, NIN1, NIN1);
    k_pack_w<<<(NG4*NIN1+255)/256, 256, 0, stream>>>(l1b_Wih, w1bp, NG4, NIN1, NIN1);
    k_pack_w<<<(NHID*NIN1+255)/256, 256, 0, stream>>>(lin1W, wl1p, NHID, NIN1, NIN1);
    // 2. features (packed)
    k_features<<<NBS, 128, 0, stream>>>(x_word, x_pos, x_char, x_enr, wembW, cembW, cnnW, cnnb, xwp);
    // 3. layer-0 input projections
    k_gemm_bf3<<<dim3(NBS/128, NG4/128), 256, 0, stream>>>(xwp, w0fp, l0f_b, zxf, NBS, NG4, NIN0P);
    k_gemm_bf3<<<dim3(NBS/128, NG4/128), 256, 0, stream>>>(xwp, w0bp, l0b_b, zxb, NBS, NG4, NIN0P);
    // 4. layer-0 recurrence (tag ring must start clean: stale tags would alias)
    hipMemsetAsync(hbf, 0, (size_t)2*2*NB*NH*sizeof(unsigned), stream);
    k_lstm_layer<<<dim3(NCHUNK, 2), 512, 0, stream>>>(zxf, zxb, l0f_Whh, l0b_Whh, h0p, hbf);
    // 5. layer-1 input projections
    k_gemm_bf3<<<dim3(NBS/128, NG4/128), 256, 0, stream>>>(h0p, w1fp, l1f_b, zxf, NBS, NG4, NIN1);
    k_gemm_bf3<<<dim3(NBS/128, NG4/128), 256, 0, stream>>>(h0p, w1bp, l1b_b, zxb, NBS, NG4, NIN1);
    // 6. layer-1 recurrence
    hipMemsetAsync(hbf, 0, (size_t)2*2*NB*NH*sizeof(unsigned), stream);
    k_lstm_layer<<<dim3(NCHUNK, 2), 512, 0, stream>>>(zxf, zxb, l1f_Whh, l1b_Whh, h1p, hbf);
    // 7. head
    k_gemm_bf3<<<dim3(NBS/128, NHID/128), 256, 0, stream>>>(h1p, wl1p, lin1b, hid1, NBS, NHID, NIN1);
    k_lin2<<<(NBS*NT+255)/256, 256, 0, stream>>>(hid1, lin2W, lin2b, em_out);
    // 8. CRF
    k_viterbi<<<NB, 64, 0, stream>>>(em_out, crf_s, crf_e, crf_tr, dec_out);
    k_nll<<<NB, 64, 0, stream>>>(em_out, y_word, crf_s, crf_e, crf_tr, partial);
    k_loss_final<<<1, 64, 0, stream>>>(partial, loss_out);
}

// Round 12
// 4783.649 us; speedup vs baseline: 1.3431x; 1.2428x over previous
//
#include <hip/hip_runtime.h>
#include <hip/hip_bf16.h>
#include <math.h>

// ---- problem dims ----
constexpr int NB   = 32;
constexpr int NS   = 256;
constexpr int NLC  = 16;
constexpr int NWD  = 256;
constexpr int NCD  = 124;
constexpr int NCO  = 32;
constexpr int NPOS = 36;
constexpr int NENR = 7;
constexpr int NH   = 512;
constexpr int NT   = 18;
constexpr int NIN0 = 331;
constexpr int NIN0P= 352;    // padded to x32
constexpr int NIN1 = 1024;
constexpr int NBS  = NB*NS;  // 8192
constexpr int NG4  = 4*NH;   // 2048
constexpr int NGS  = 4096;   // fused zx row stride (fwd 2048 | bwd 2048)
constexpr int NHID = 128;
constexpr int NCHUNK = 16;   // unit-chunks per dir (32 units each)

typedef __attribute__((ext_vector_type(8))) short short8v;
typedef __attribute__((ext_vector_type(4))) float f32x4;

__device__ __forceinline__ float sigmoidf_(float x){ return 1.0f/(1.0f+expf(-x)); }
__device__ __forceinline__ short f2bf(float f) {
    union { __hip_bfloat16 h; short s; } u;
    u.h = __float2bfloat16(f);
    return u.s;
}
__device__ __forceinline__ float bf2f(short s) {
    union { unsigned u; float f; } v;
    v.u = ((unsigned)(unsigned short)s) << 16;
    return v.f;
}
__device__ __forceinline__ unsigned packbf3(float v) {
    short hi = f2bf(v);
    short lo = f2bf(v - bf2f(hi));
    return ((unsigned)(unsigned short)hi << 16) | (unsigned short)lo;
}
// 8 packed u32 -> hi/lo bf16 fragments (lstm exchange path only)
__device__ __forceinline__ void unpack8(const unsigned* w, short8v& hi, short8v& lo) {
    union U { short8v s; unsigned u[4]; } H, L;
    #pragma unroll
    for (int i = 0; i < 4; i++) {
        H.u[i] = (w[2*i+1] & 0xFFFF0000u) | (w[2*i] >> 16);
        L.u[i] = (w[2*i+1] << 16) | (w[2*i] & 0xFFFFu);
    }
    hi = H.s; lo = L.s;
}
// relaxed agent-scope ops (sc1 path, no cache maintenance) — proven in r6
__device__ __forceinline__ unsigned ld_sc1(const unsigned* p) {
    return __hip_atomic_load(p, __ATOMIC_RELAXED, __HIP_MEMORY_SCOPE_AGENT);
}
__device__ __forceinline__ void st_sc1(unsigned* p, unsigned v) {
    __hip_atomic_store(p, v, __ATOMIC_RELAXED, __HIP_MEMORY_SCOPE_AGENT);
}

// -------- features: word embed + char CNN + concat + relu -> hi/lo bf16 planes ----
__global__ __launch_bounds__(128) void k_features(const int* __restrict__ x_word,
    const float* __restrict__ x_pos, const int* __restrict__ x_char,
    const float* __restrict__ x_enr, const float* __restrict__ wembW,
    const float* __restrict__ cembW, const float* __restrict__ cnnW,
    const float* __restrict__ cnnb,
    unsigned short* __restrict__ xh, unsigned short* __restrict__ xl)
{
    __shared__ float ce[NLC][NCD];
    __shared__ float cv[NCO][13];
    __shared__ float cpool[NCO];
    int n = blockIdx.x;
    int tid = threadIdx.x;
    for (int i = tid; i < NLC*NCD; i += 128) {
        int l = i / NCD, c = i % NCD;
        ce[l][c] = cembW[x_char[n*NLC + l]*NCD + c];
    }
    __syncthreads();
    for (int p = tid; p < NCO*12; p += 128) {
        int o = p & 31, t = p >> 5;
        const float* wr = cnnW + o*NCD*5;
        float acc = 0.f;
        for (int c = 0; c < NCD; c++) {
            #pragma unroll
            for (int k = 0; k < 5; k++) acc += ce[t+k][c] * wr[c*5+k];
        }
        cv[o][t] = acc;
    }
    __syncthreads();
    if (tid < NCO) {
        float m = cv[tid][0];
        #pragma unroll
        for (int t = 1; t < 12; t++) m = fmaxf(m, cv[tid][t]);
        cpool[tid] = m + cnnb[tid];
    }
    __syncthreads();
    int widx = x_word[n];
    for (int j = tid; j < NIN0P; j += 128) {
        float v;
        if (j < NWD)            v = wembW[(size_t)widx*NWD + j];
        else if (j < NWD+NPOS)  v = x_pos[n*NPOS + (j-NWD)];
        else if (j < NWD+NPOS+NCO) v = cpool[j-(NWD+NPOS)];
        else if (j < NIN0)      v = x_enr[n*NENR + (j-(NWD+NPOS+NCO))];
        else                    v = 0.f;
        v = fmaxf(v, 0.f);
        short hi = f2bf(v);
        xh[(size_t)n*NIN0P + j] = (unsigned short)hi;
        xl[(size_t)n*NIN0P + j] = (unsigned short)f2bf(v - bf2f(hi));
    }
}

// -------- pack f32 weight [N][Ksrc] -> hi/lo bf16 planes [N][Kdst] (zero pad) ----
__global__ void k_pack_w(const float* __restrict__ W,
                         unsigned short* __restrict__ Wh, unsigned short* __restrict__ Wl,
                         int N, int Ksrc, int Kdst)
{
    int idx = blockIdx.x*256 + threadIdx.x;
    if (idx >= N*Kdst) return;
    int n = idx / Kdst, k = idx % Kdst;
    float v = (k < Ksrc) ? W[(size_t)n*Ksrc + k] : 0.f;
    short hi = f2bf(v);
    Wh[idx] = (unsigned short)hi;
    Wl[idx] = (unsigned short)f2bf(v - bf2f(hi));
}

// -------- split-plane bf16x3 MFMA GEMM: C[M,N] = A@W^T + bias ----------------
// A,W as separate hi/lo bf16 planes -> ds_read_b128 gives fragments directly
// (no unpack VALU). Linear [128][32]-short LDS tiles, 16B-unit XOR swizzle
// u^(row&3): bank-group 16(lr&1)+4(lk^(lr&3)) -> 2 lanes/bank = free.
constexpr int HBK = 32;
__global__ __launch_bounds__(256, 2) void k_gemm_hl(
    const unsigned short* __restrict__ Ah, const unsigned short* __restrict__ Al,
    const unsigned short* __restrict__ Bh, const unsigned short* __restrict__ Bl,
    const float* __restrict__ bias, float* __restrict__ C,
    int M, int N, int K)
{
    __shared__ unsigned short sAh[128*HBK], sAl[128*HBK];
    __shared__ unsigned short sBh[128*HBK], sBl[128*HBK];
    int bm = blockIdx.x*128, bn = blockIdx.y*128;
    int tid = threadIdx.x;
    int l = tid & 63, wv = tid >> 6;
    int wm = wv >> 1, wn = wv & 1;
    int lr = l & 15, lk = l >> 4;

    f32x4 acc[4][4];
    #pragma unroll
    for (int i = 0; i < 4; i++)
        #pragma unroll
        for (int j = 0; j < 4; j++) acc[i][j] = (f32x4){0.f,0.f,0.f,0.f};

    uint4 r[8];
    int KT = K / HBK;
    {
        #pragma unroll
        for (int i = 0; i < 2; i++) {
            int s = i*256 + tid, row = s >> 2, u0 = s & 3;
            r[i]   = *(const uint4*)(Ah + (size_t)(bm+row)*K + u0*8);
            r[2+i] = *(const uint4*)(Al + (size_t)(bm+row)*K + u0*8);
            r[4+i] = *(const uint4*)(Bh + (size_t)(bn+row)*K + u0*8);
            r[6+i] = *(const uint4*)(Bl + (size_t)(bn+row)*K + u0*8);
        }
    }
    for (int kt = 0; kt < KT; kt++) {
        #pragma unroll
        for (int i = 0; i < 2; i++) {
            int s = i*256 + tid, row = s >> 2, u0 = s & 3, su = u0 ^ (row & 3);
            *(uint4*)&sAh[row*HBK + su*8] = r[i];
            *(uint4*)&sAl[row*HBK + su*8] = r[2+i];
            *(uint4*)&sBh[row*HBK + su*8] = r[4+i];
            *(uint4*)&sBl[row*HBK + su*8] = r[6+i];
        }
        __syncthreads();
        if (kt+1 < KT) {
            #pragma unroll
            for (int i = 0; i < 2; i++) {
                int s = i*256 + tid, row = s >> 2, u0 = s & 3;
                r[i]   = *(const uint4*)(Ah + (size_t)(bm+row)*K + (kt+1)*HBK + u0*8);
                r[2+i] = *(const uint4*)(Al + (size_t)(bm+row)*K + (kt+1)*HBK + u0*8);
                r[4+i] = *(const uint4*)(Bh + (size_t)(bn+row)*K + (kt+1)*HBK + u0*8);
                r[6+i] = *(const uint4*)(Bl + (size_t)(bn+row)*K + (kt+1)*HBK + u0*8);
            }
        }
        short8v fAh[4], fAl[4], fBh[4], fBl[4];
        #pragma unroll
        for (int f = 0; f < 4; f++) {
            int ra = wm*64 + f*16 + lr, ua = lk ^ (ra & 3);
            fAh[f] = *(const short8v*)&sAh[ra*HBK + ua*8];
            fAl[f] = *(const short8v*)&sAl[ra*HBK + ua*8];
            int rb = wn*64 + f*16 + lr, ub = lk ^ (rb & 3);
            fBh[f] = *(const short8v*)&sBh[rb*HBK + ub*8];
            fBl[f] = *(const short8v*)&sBl[rb*HBK + ub*8];
        }
        #pragma unroll
        for (int i = 0; i < 4; i++)
            #pragma unroll
            for (int j = 0; j < 4; j++) {
                acc[i][j] = __builtin_amdgcn_mfma_f32_16x16x32_bf16(fAh[i], fBh[j], acc[i][j], 0, 0, 0);
                acc[i][j] = __builtin_amdgcn_mfma_f32_16x16x32_bf16(fAl[i], fBh[j], acc[i][j], 0, 0, 0);
                acc[i][j] = __builtin_amdgcn_mfma_f32_16x16x32_bf16(fAh[i], fBl[j], acc[i][j], 0, 0, 0);
            }
        __syncthreads();
    }
    #pragma unroll
    for (int i = 0; i < 4; i++) {
        int m0 = bm + wm*64 + i*16 + lk*4;
        #pragma unroll
        for (int j = 0; j < 4; j++) {
            int n0 = bn + wn*64 + j*16 + lr;
            float bv = bias[n0];
            #pragma unroll
            for (int q = 0; q < 4; q++)
                C[(size_t)(m0+q)*N + n0] = acc[i][j][q] + bv;
        }
    }
}

// ---------------- persistent LSTM layer (r6 structure, best measured) ----------
// 16 chunks x 2 dirs, 512 thr, 8 waves = 4 gates x 2 K-halves (split-K).
// Relaxed agent-scope (sc1) exchange; burst LDS stage; per-chunk flags with
// block-drain release (3 barriers/step). Changes vs r6: zx stride NGS (fused
// buffer), h output as hi/lo planes (off critical path).
__global__ __launch_bounds__(512, 2) void k_lstm_layer(
    const float* __restrict__ zxcat,
    const float* __restrict__ Whh_f, const float* __restrict__ Whh_b,
    unsigned short* __restrict__ h_hi, unsigned short* __restrict__ h_lo,
    unsigned* __restrict__ hbf, unsigned* __restrict__ flags)
{
    int chunk = blockIdx.x;        // 0..15 (32 hidden units each)
    int dir   = blockIdx.y;
    int tid = threadIdx.x;
    int wv = tid >> 6, l = tid & 63;
    int g  = wv & 3;               // gate
    int ks = wv >> 2;              // K-half (0/1)
    int lr = l & 15, lk = l >> 4;
    const float* zx  = zxcat + dir*NG4;     // fwd cols 0..2047, bwd 2048..4095
    const float* Whh = dir ? Whh_b : Whh_f;
    unsigned* hb = hbf + (size_t)dir * (2*NB*NH);
    unsigned* flag = flags + (size_t)dir * NCHUNK * 16;   // 64B stride per chunk

    // ---- preload Whh slice: gate g, units chunk*32+uh*16+lr, k-half ks ----
    short8v bwh[2][8], bwl[2][8];
    #pragma unroll
    for (int uh = 0; uh < 2; uh++) {
        const float* wrow = Whh + ((size_t)(g*NH + chunk*32 + uh*16 + lr))*NH + ks*256 + lk*8;
        #pragma unroll
        for (int kt = 0; kt < 8; kt++) {
            float u[8];
            *(float4*)&u[0] = *(const float4*)(wrow + kt*32);
            *(float4*)&u[4] = *(const float4*)(wrow + kt*32 + 4);
            short8v sh, sl;
            #pragma unroll
            for (int j = 0; j < 8; j++) {
                short hi = f2bf(u[j]);
                sh[j] = hi;
                sl[j] = f2bf(u[j] - bf2f(hi));
            }
            bwh[uh][kt] = sh; bwl[uh][kt] = sl;
        }
    }

    __shared__ unsigned hstage[32*516];      // h_prev staged per block
    __shared__ float zsh[2][4][32][33];      // [ks][gate][batch][unit] partials
    float c0 = 0.f, c1 = 0.f;

    for (int t = 0; t < NS; t++) {
        int t_eff = dir ? (NS-1-t) : t;

        // ---- prefetch zx into regs (independent of the flag) ----
        float pz[2][4];
        #pragma unroll
        for (int cc = 0; cc < 2; cc++) {
            int cell = tid + cc*512, b = cell >> 5, u = cell & 31;
            const float* zr = zx + ((size_t)(b*NS + t_eff))*NGS + chunk*32 + u;
            #pragma unroll
            for (int g2 = 0; g2 < 4; g2++) pz[cc][g2] = zr[g2*NH];
        }

        if (t > 0) {
            // ---- poll all 16 chunk flags (relaxed sc1) ----
            {
                const unsigned* fp = &flag[(l & 15)*16];
                unsigned v;
                do { v = ld_sc1(fp); } while (!__all((int)(v >= (unsigned)t)));
                asm volatile("" ::: "memory");
            }
            // ---- burst stage hb slot -> LDS (coalesced sc1 dword loads) ----
            const unsigned* hp = hb + ((t-1)&1)*(NB*NH);
            unsigned sv[32];
            #pragma unroll
            for (int i = 0; i < 32; i++) sv[i] = ld_sc1(hp + i*512 + tid);
            #pragma unroll
            for (int i = 0; i < 32; i++) hstage[i*516 + tid] = sv[i];
        }
        __syncthreads();   // barrier A: stage visible

        // ---- split-K MFMA: wave covers k in [ks*256, ks*256+256) ----
        f32x4 acc[2][2][3];
        #pragma unroll
        for (int bh = 0; bh < 2; bh++)
            #pragma unroll
            for (int uh = 0; uh < 2; uh++)
                #pragma unroll
                for (int q = 0; q < 3; q++) acc[bh][uh][q] = (f32x4){0.f,0.f,0.f,0.f};
        if (t > 0) {
            #pragma unroll
            for (int kt = 0; kt < 8; kt++) {
                short8v ah[2], al[2];
                #pragma unroll
                for (int bh = 0; bh < 2; bh++) {
                    unsigned w8[8];
                    const unsigned* sp = hstage + (bh*16+lr)*516 + ks*256 + kt*32 + lk*8;
                    *(uint4*)&w8[0] = *(const uint4*)sp;
                    *(uint4*)&w8[4] = *(const uint4*)(sp+4);
                    unpack8(w8, ah[bh], al[bh]);
                }
                #pragma unroll
                for (int bh = 0; bh < 2; bh++)
                    #pragma unroll
                    for (int uh = 0; uh < 2; uh++) {
                        acc[bh][uh][0] = __builtin_amdgcn_mfma_f32_16x16x32_bf16(ah[bh], bwh[uh][kt], acc[bh][uh][0], 0, 0, 0);
                        acc[bh][uh][1] = __builtin_amdgcn_mfma_f32_16x16x32_bf16(al[bh], bwh[uh][kt], acc[bh][uh][1], 0, 0, 0);
                        acc[bh][uh][2] = __builtin_amdgcn_mfma_f32_16x16x32_bf16(ah[bh], bwl[uh][kt], acc[bh][uh][2], 0, 0, 0);
                    }
            }
        }
        // C layout: col=lane&15 -> unit uh*16+lr, row=(lane>>4)*4+j -> batch
        #pragma unroll
        for (int bh = 0; bh < 2; bh++)
            #pragma unroll
            for (int uh = 0; uh < 2; uh++)
                #pragma unroll
                for (int j = 0; j < 4; j++)
                    zsh[ks][g][bh*16 + lk*4 + j][uh*16 + lr] =
                        acc[bh][uh][0][j] + acc[bh][uh][1][j] + acc[bh][uh][2][j];
        __syncthreads();   // barrier B: zsh ready

        // ---- epilogue: 1024 cells / 512 threads ----
        unsigned hq0 = 0, hq1 = 0;
        #pragma unroll
        for (int cc = 0; cc < 2; cc++) {
            int cell = tid + cc*512, b = cell >> 5, u = cell & 31;
            float zi = pz[cc][0] + zsh[0][0][b][u] + zsh[1][0][b][u];
            float zf = pz[cc][1] + zsh[0][1][b][u] + zsh[1][1][b][u];
            float zg = pz[cc][2] + zsh[0][2][b][u] + zsh[1][2][b][u];
            float zo = pz[cc][3] + zsh[0][3][b][u] + zsh[1][3][b][u];
            float cold = cc ? c1 : c0;
            float cn = sigmoidf_(zf)*cold + sigmoidf_(zi)*tanhf(zg);
            float hn = sigmoidf_(zo)*tanhf(cn);
            unsigned pk = packbf3(hn);
            if (cc) { c1 = cn; hq1 = pk; } else { c0 = cn; hq0 = pk; }
            st_sc1(&hb[(size_t)(t&1)*(NB*NH) + b*NH + chunk*32 + u], pk);
        }
        // barrier drains all waves' hb stores (implicit vmcnt(0)) + protects zsh
        __syncthreads();   // barrier C
        if (tid == 0)
            st_sc1(&flag[chunk*16], (unsigned)(t+1));
        // h hi/lo planes for downstream GEMMs (off critical path)
        #pragma unroll
        for (int cc = 0; cc < 2; cc++) {
            int cell = tid + cc*512, b = cell >> 5, u = cell & 31;
            unsigned pk = cc ? hq1 : hq0;
            size_t o = ((size_t)(b*NS + t_eff))*NIN1 + dir*NH + chunk*32 + u;
            h_hi[o] = (unsigned short)(pk >> 16);
            h_lo[o] = (unsigned short)(pk & 0xFFFFu);
        }
    }
}

// ---------------- emissions: em = hid1 @ lin2W^T + b2 ----------------
__global__ __launch_bounds__(256) void k_lin2(const float* __restrict__ hid,
    const float* __restrict__ W2, const float* __restrict__ b2, float* __restrict__ em)
{
    int flat = blockIdx.x*256 + threadIdx.x;
    if (flat >= NBS*NT) return;
    int m = flat / NT, j = flat % NT;
    const float* hr = hid + (size_t)m*NHID;
    const float* wr = W2 + j*NHID;
    float acc = b2[j];
    #pragma unroll 8
    for (int k = 0; k < NHID; k += 4) {
        float4 h4 = *(const float4*)(hr+k);
        float4 w4 = *(const float4*)(wr+k);
        acc += h4.x*w4.x + h4.y*w4.y + h4.z*w4.z + h4.w*w4.w;
    }
    em[flat] = acc;
}

// ---------------- viterbi decode (one wave per batch item) ----------------
__global__ __launch_bounds__(64) void k_viterbi(const float* __restrict__ em,
    const float* __restrict__ start, const float* __restrict__ endv,
    const float* __restrict__ trans, float* __restrict__ dec)
{
    __shared__ float sc[NT];
    __shared__ float tr[NT][NT];
    __shared__ unsigned char hist[NS][NT];
    int b = blockIdx.x, tid = threadIdx.x;
    for (int i = tid; i < NT*NT; i += 64) tr[i/NT][i%NT] = trans[i];
    if (tid < NT) sc[tid] = start[tid] + em[((size_t)b*NS)*NT + tid];
    __syncthreads();
    for (int t = 1; t < NS; t++) {
        float best = -1e30f; int bi = 0;
        if (tid < NT) {
            for (int i = 0; i < NT; i++) {
                float v = sc[i] + tr[i][tid];
                if (v > best) { best = v; bi = i; }
            }
            hist[t][tid] = (unsigned char)bi;
            best += em[((size_t)b*NS + t)*NT + tid];
        }
        __syncthreads();
        if (tid < NT) sc[tid] = best;
        __syncthreads();
    }
    if (tid == 0) {
        float bv = sc[0] + endv[0]; int tag = 0;
        for (int j = 1; j < NT; j++) { float v = sc[j] + endv[j]; if (v > bv) { bv = v; tag = j; } }
        dec[b*NS + NS-1] = (float)tag;
        for (int t = NS-1; t >= 1; t--) { tag = hist[t][tag]; dec[b*NS + t-1] = (float)tag; }
    }
}

// ---------------- CRF NLL (mask is all ones) ----------------
__global__ __launch_bounds__(64) void k_nll(const float* __restrict__ em,
    const int* __restrict__ tags, const float* __restrict__ start,
    const float* __restrict__ endv, const float* __restrict__ trans,
    float* __restrict__ partial)
{
    __shared__ float sc[NT];
    __shared__ float tr[NT][NT];
    int b = blockIdx.x, tid = threadIdx.x;
    for (int i = tid; i < NT*NT; i += 64) tr[i/NT][i%NT] = trans[i];
    if (tid < NT) sc[tid] = start[tid] + em[((size_t)b*NS)*NT + tid];
    __syncthreads();
    for (int t = 1; t < NS; t++) {
        float nv = 0.f;
        if (tid < NT) {
            float m = -1e30f;
            for (int i = 0; i < NT; i++) m = fmaxf(m, sc[i] + tr[i][tid]);
            float s = 0.f;
            for (int i = 0; i < NT; i++) s += expf(sc[i] + tr[i][tid] - m);
            nv = m + logf(s) + em[((size_t)b*NS + t)*NT + tid];
        }
        __syncthreads();
        if (tid < NT) sc[tid] = nv;
        __syncthreads();
    }
    if (tid == 0) {
        float m = -1e30f;
        for (int j = 0; j < NT; j++) m = fmaxf(m, sc[j] + endv[j]);
        float s = 0.f;
        for (int j = 0; j < NT; j++) s += expf(sc[j] + endv[j] - m);
        float logZ = m + logf(s);
        const int* tg = tags + b*NS;
        float num = start[tg[0]] + em[((size_t)b*NS)*NT + tg[0]];
        for (int t = 1; t < NS; t++)
            num += tr[tg[t-1]][tg[t]] + em[((size_t)b*NS + t)*NT + tg[t]];
        num += endv[tg[NS-1]];
        partial[b] = -(num - logZ);
    }
}

__global__ void k_loss_final(const float* __restrict__ partial, float* __restrict__ loss)
{
    if (threadIdx.x == 0 && blockIdx.x == 0) {
        float s = 0.f;
        for (int b = 0; b < NB; b++) s += partial[b];
        *loss = s / (float)(NB*NS);
    }
}

extern "C" void kernel_launch(void* const* d_in, const int* in_sizes, int n_in,
                              void* d_out, int out_size, void* d_ws, size_t ws_size,
                              hipStream_t stream)
{
    const int*   x_word = (const int*)d_in[0];
    const float* x_pos  = (const float*)d_in[1];
    const int*   x_char = (const int*)d_in[2];
    const float* x_enr  = (const float*)d_in[3];
    const int*   y_word = (const int*)d_in[5];
    const float* wembW  = (const float*)d_in[6];
    const float* cembW  = (const float*)d_in[7];
    const float* cnnW   = (const float*)d_in[8];
    const float* cnnb   = (const float*)d_in[9];
    const float* lin1W  = (const float*)d_in[10];
    const float* lin1b  = (const float*)d_in[11];
    const float* lin2W  = (const float*)d_in[12];
    const float* lin2b  = (const float*)d_in[13];
    const float* crf_s  = (const float*)d_in[14];
    const float* crf_e  = (const float*)d_in[15];
    const float* crf_tr = (const float*)d_in[16];
    const float* l0f_Wih = (const float*)d_in[17];
    const float* l0f_Whh = (const float*)d_in[18];
    const float* l0f_b   = (const float*)d_in[19];
    const float* l0b_Wih = (const float*)d_in[20];
    const float* l0b_Whh = (const float*)d_in[21];
    const float* l0b_b   = (const float*)d_in[22];
    const float* l1f_Wih = (const float*)d_in[23];
    const float* l1f_Whh = (const float*)d_in[24];
    const float* l1f_b   = (const float*)d_in[25];
    const float* l1b_Wih = (const float*)d_in[26];
    const float* l1b_Whh = (const float*)d_in[27];
    const float* l1b_b   = (const float*)d_in[28];

    char* wsb = (char*)d_ws;
    size_t off = 0;
    auto alloc = [&](size_t bytes) { char* p = wsb + off; off += (bytes + 255) & ~(size_t)255; return p; };
    unsigned short* xh  = (unsigned short*)alloc((size_t)NBS*NIN0P*2);
    unsigned short* xl  = (unsigned short*)alloc((size_t)NBS*NIN0P*2);
    unsigned short* w0h = (unsigned short*)alloc((size_t)NGS*NIN0P*2);
    unsigned short* w0l = (unsigned short*)alloc((size_t)NGS*NIN0P*2);
    unsigned short* w1h = (unsigned short*)alloc((size_t)NGS*NIN1*2);
    unsigned short* w1l = (unsigned short*)alloc((size_t)NGS*NIN1*2);
    unsigned short* wlh = (unsigned short*)alloc((size_t)NHID*NIN1*2);
    unsigned short* wll = (unsigned short*)alloc((size_t)NHID*NIN1*2);
    float*    zxcat = (float*)alloc((size_t)NBS*NGS*4);
    unsigned short* h0h = (unsigned short*)alloc((size_t)NBS*NIN1*2);
    unsigned short* h0l = (unsigned short*)alloc((size_t)NBS*NIN1*2);
    unsigned short* h1h = (unsigned short*)alloc((size_t)NBS*NIN1*2);
    unsigned short* h1l = (unsigned short*)alloc((size_t)NBS*NIN1*2);
    float*    hid1  = (float*)alloc((size_t)NBS*NHID*4);
    float*    partial = (float*)alloc(256);
    float*    bias0 = (float*)alloc((size_t)NGS*4);
    float*    bias1 = (float*)alloc((size_t)NGS*4);
    unsigned* hbf   = (unsigned*)alloc((size_t)2*2*NB*NH*4);
    unsigned* flags = (unsigned*)alloc((size_t)2*NCHUNK*16*4);

    float* em_out   = (float*)d_out;
    float* dec_out  = em_out + (size_t)NBS*NT;
    float* loss_out = dec_out + NBS;

    // 1. pack weights into hi/lo planes (cat fwd|bwd rows)
    k_pack_w<<<(NG4*NIN0P+255)/256, 256, 0, stream>>>(l0f_Wih, w0h, w0l, NG4, NIN0, NIN0P);
    k_pack_w<<<(NG4*NIN0P+255)/256, 256, 0, stream>>>(l0b_Wih, w0h + (size_t)NG4*NIN0P, w0l + (size_t)NG4*NIN0P, NG4, NIN0, NIN0P);
    k_pack_w<<<(NG4*NIN1+255)/256, 256, 0, stream>>>(l1f_Wih, w1h, w1l, NG4, NIN1, NIN1);
    k_pack_w<<<(NG4*NIN1+255)/256, 256, 0, stream>>>(l1b_Wih, w1h + (size_t)NG4*NIN1, w1l + (size_t)NG4*NIN1, NG4, NIN1, NIN1);
    k_pack_w<<<(NHID*NIN1+255)/256, 256, 0, stream>>>(lin1W, wlh, wll, NHID, NIN1, NIN1);
    // cat biases
    hipMemcpyAsync(bias0,       l0f_b, NG4*4, hipMemcpyDeviceToDevice, stream);
    hipMemcpyAsync(bias0 + NG4, l0b_b, NG4*4, hipMemcpyDeviceToDevice, stream);
    hipMemcpyAsync(bias1,       l1f_b, NG4*4, hipMemcpyDeviceToDevice, stream);
    hipMemcpyAsync(bias1 + NG4, l1b_b, NG4*4, hipMemcpyDeviceToDevice, stream);
    // 2. features (hi/lo planes)
    k_features<<<NBS, 128, 0, stream>>>(x_word, x_pos, x_char, x_enr, wembW, cembW, cnnW, cnnb, xh, xl);
    // 3. layer-0 fused input projection (both dirs, N=4096)
    k_gemm_hl<<<dim3(NBS/128, NGS/128), 256, 0, stream>>>(xh, xl, w0h, w0l, bias0, zxcat, NBS, NGS, NIN0P);
    // 4. layer-0 recurrence
    hipMemsetAsync(flags, 0, (size_t)2*NCHUNK*16*4, stream);
    k_lstm_layer<<<dim3(NCHUNK, 2), 512, 0, stream>>>(zxcat, l0f_Whh, l0b_Whh, h0h, h0l, hbf, flags);
    // 5. layer-1 fused input projection
    k_gemm_hl<<<dim3(NBS/128, NGS/128), 256, 0, stream>>>(h0h, h0l, w1h, w1l, bias1, zxcat, NBS, NGS, NIN1);
    // 6. layer-1 recurrence
    hipMemsetAsync(flags, 0, (size_t)2*NCHUNK*16*4, stream);
    k_lstm_layer<<<dim3(NCHUNK, 2), 512, 0, stream>>>(zxcat, l1f_Whh, l1b_Whh, h1h, h1l, hbf, flags);
    // 7. head
    k_gemm_hl<<<dim3(NBS/128, NHID/128), 256, 0, stream>>>(h1h, h1l, wlh, wll, lin1b, hid1, NBS, NHID, NIN1);
    k_lin2<<<(NBS*NT+255)/256, 256, 0, stream>>>(hid1, lin2W, lin2b, em_out);
    // 8. CRF
    k_viterbi<<<NB, 64, 0, stream>>>(em_out, crf_s, crf_e, crf_tr, dec_out);
    k_nll<<<NB, 64, 0, stream>>>(em_out, y_word, crf_s, crf_e, crf_tr, partial);
    k_loss_final<<<1, 64, 0, stream>>>(partial, loss_out);
}

// Round 13
// 4514.143 us; speedup vs baseline: 1.4232x; 1.0597x over previous
//
#include <hip/hip_runtime.h>
#include <hip/hip_bf16.h>
#include <math.h>

// ---- problem dims ----
constexpr int NB   = 32;
constexpr int NS   = 256;
constexpr int NLC  = 16;
constexpr int NWD  = 256;
constexpr int NCD  = 124;
constexpr int NCO  = 32;
constexpr int NPOS = 36;
constexpr int NENR = 7;
constexpr int NH   = 512;
constexpr int NT   = 18;
constexpr int NIN0 = 331;
constexpr int NIN0P= 352;    // padded to x32
constexpr int NIN1 = 1024;
constexpr int NBS  = NB*NS;  // 8192
constexpr int NG4  = 4*NH;   // 2048
constexpr int NGS  = 4096;   // fused zx row stride (fwd 2048 | bwd 2048)
constexpr int NHID = 128;
constexpr int NCHUNK = 16;   // unit-chunks per dir (32 units each)

typedef __attribute__((ext_vector_type(8))) short short8v;
typedef __attribute__((ext_vector_type(4))) float f32x4;

__device__ __forceinline__ float sigmoidf_(float x){ return 1.0f/(1.0f+expf(-x)); }
__device__ __forceinline__ short f2bf(float f) {
    union { __hip_bfloat16 h; short s; } u;
    u.h = __float2bfloat16(f);
    return u.s;
}
__device__ __forceinline__ float bf2f(short s) {
    union { unsigned u; float f; } v;
    v.u = ((unsigned)(unsigned short)s) << 16;
    return v.f;
}
__device__ __forceinline__ unsigned packbf3(float v) {
    short hi = f2bf(v);
    short lo = f2bf(v - bf2f(hi));
    return ((unsigned)(unsigned short)hi << 16) | (unsigned short)lo;
}
// 8 packed u32 -> hi/lo bf16 fragments (lstm exchange path only)
__device__ __forceinline__ void unpack8(const unsigned* w, short8v& hi, short8v& lo) {
    union U { short8v s; unsigned u[4]; } H, L;
    #pragma unroll
    for (int i = 0; i < 4; i++) {
        H.u[i] = (w[2*i+1] & 0xFFFF0000u) | (w[2*i] >> 16);
        L.u[i] = (w[2*i+1] << 16) | (w[2*i] & 0xFFFFu);
    }
    hi = H.s; lo = L.s;
}
// relaxed agent-scope ops (sc1 path, no cache maintenance) — proven in r6
__device__ __forceinline__ unsigned ld_sc1(const unsigned* p) {
    return __hip_atomic_load(p, __ATOMIC_RELAXED, __HIP_MEMORY_SCOPE_AGENT);
}
__device__ __forceinline__ void st_sc1(unsigned* p, unsigned v) {
    __hip_atomic_store(p, v, __ATOMIC_RELAXED, __HIP_MEMORY_SCOPE_AGENT);
}

// -------- features: word embed + char CNN + concat + relu -> hi/lo bf16 planes ----
__global__ __launch_bounds__(128) void k_features(const int* __restrict__ x_word,
    const float* __restrict__ x_pos, const int* __restrict__ x_char,
    const float* __restrict__ x_enr, const float* __restrict__ wembW,
    const float* __restrict__ cembW, const float* __restrict__ cnnW,
    const float* __restrict__ cnnb,
    unsigned short* __restrict__ xh, unsigned short* __restrict__ xl)
{
    __shared__ float ce[NLC][NCD];
    __shared__ float cv[NCO][13];
    __shared__ float cpool[NCO];
    int n = blockIdx.x;
    int tid = threadIdx.x;
    for (int i = tid; i < NLC*NCD; i += 128) {
        int l = i / NCD, c = i % NCD;
        ce[l][c] = cembW[x_char[n*NLC + l]*NCD + c];
    }
    __syncthreads();
    for (int p = tid; p < NCO*12; p += 128) {
        int o = p & 31, t = p >> 5;
        const float* wr = cnnW + o*NCD*5;
        float acc = 0.f;
        for (int c = 0; c < NCD; c++) {
            #pragma unroll
            for (int k = 0; k < 5; k++) acc += ce[t+k][c] * wr[c*5+k];
        }
        cv[o][t] = acc;
    }
    __syncthreads();
    if (tid < NCO) {
        float m = cv[tid][0];
        #pragma unroll
        for (int t = 1; t < 12; t++) m = fmaxf(m, cv[tid][t]);
        cpool[tid] = m + cnnb[tid];
    }
    __syncthreads();
    int widx = x_word[n];
    for (int j = tid; j < NIN0P; j += 128) {
        float v;
        if (j < NWD)            v = wembW[(size_t)widx*NWD + j];
        else if (j < NWD+NPOS)  v = x_pos[n*NPOS + (j-NWD)];
        else if (j < NWD+NPOS+NCO) v = cpool[j-(NWD+NPOS)];
        else if (j < NIN0)      v = x_enr[n*NENR + (j-(NWD+NPOS+NCO))];
        else                    v = 0.f;
        v = fmaxf(v, 0.f);
        short hi = f2bf(v);
        xh[(size_t)n*NIN0P + j] = (unsigned short)hi;
        xl[(size_t)n*NIN0P + j] = (unsigned short)f2bf(v - bf2f(hi));
    }
}

// -------- pack f32 weight [N][Ksrc] -> hi/lo bf16 planes [N][Kdst] (zero pad) ----
__global__ void k_pack_w(const float* __restrict__ W,
                         unsigned short* __restrict__ Wh, unsigned short* __restrict__ Wl,
                         int N, int Ksrc, int Kdst)
{
    int idx = blockIdx.x*256 + threadIdx.x;
    if (idx >= N*Kdst) return;
    int n = idx / Kdst, k = idx % Kdst;
    float v = (k < Ksrc) ? W[(size_t)n*Ksrc + k] : 0.f;
    short hi = f2bf(v);
    Wh[idx] = (unsigned short)hi;
    Wl[idx] = (unsigned short)f2bf(v - bf2f(hi));
}

// -------- split-plane bf16x3 MFMA GEMM: C[M,N] = A@W^T + bias ----------------
// r13: ping-pong LDS (64 KB), ONE barrier/kt, prefetch issued one full
// iteration ahead (loads for kt+2 at iteration kt, consumed by ds_write at
// kt+1) -> ~600+ cyc load-use distance with a single register set.
// 16B-unit XOR swizzle u^(row&3) keeps MFMA ds_read_b128 conflict-free.
constexpr int HBK = 32;
__global__ __launch_bounds__(256, 2) void k_gemm_hl(
    const unsigned short* __restrict__ Ah, const unsigned short* __restrict__ Al,
    const unsigned short* __restrict__ Bh, const unsigned short* __restrict__ Bl,
    const float* __restrict__ bias, float* __restrict__ C,
    int M, int N, int K)
{
    __shared__ unsigned short sA[2][2][128*HBK];   // [buf][hi/lo] 32 KB
    __shared__ unsigned short sB[2][2][128*HBK];   // 32 KB
    int bm = blockIdx.x*128, bn = blockIdx.y*128;
    int tid = threadIdx.x;
    int l = tid & 63, wv = tid >> 6;
    int wm = wv >> 1, wn = wv & 1;
    int lr = l & 15, lk = l >> 4;

    f32x4 acc[4][4];
    #pragma unroll
    for (int i = 0; i < 4; i++)
        #pragma unroll
        for (int j = 0; j < 4; j++) acc[i][j] = (f32x4){0.f,0.f,0.f,0.f};

    int KT = K / HBK;
    uint4 r[8];
    // lane -> (row, u0) for staging
    int srow0 = tid >> 2, su0 = tid & 3;
    int srow1 = (256 + tid) >> 2, su1 = tid & 3;   // rows 64..127

    auto loadregs = [&](int kt) {
        size_t ca = (size_t)kt*HBK;
        r[0] = *(const uint4*)(Ah + (size_t)(bm+srow0)*K + ca + su0*8);
        r[1] = *(const uint4*)(Ah + (size_t)(bm+srow1)*K + ca + su1*8);
        r[2] = *(const uint4*)(Al + (size_t)(bm+srow0)*K + ca + su0*8);
        r[3] = *(const uint4*)(Al + (size_t)(bm+srow1)*K + ca + su1*8);
        r[4] = *(const uint4*)(Bh + (size_t)(bn+srow0)*K + ca + su0*8);
        r[5] = *(const uint4*)(Bh + (size_t)(bn+srow1)*K + ca + su1*8);
        r[6] = *(const uint4*)(Bl + (size_t)(bn+srow0)*K + ca + su0*8);
        r[7] = *(const uint4*)(Bl + (size_t)(bn+srow1)*K + ca + su1*8);
    };
    auto stores = [&](int buf) {
        int sw0 = (su0 ^ (srow0 & 3))*8, sw1 = (su1 ^ (srow1 & 3))*8;
        *(uint4*)&sA[buf][0][srow0*HBK + sw0] = r[0];
        *(uint4*)&sA[buf][0][srow1*HBK + sw1] = r[1];
        *(uint4*)&sA[buf][1][srow0*HBK + sw0] = r[2];
        *(uint4*)&sA[buf][1][srow1*HBK + sw1] = r[3];
        *(uint4*)&sB[buf][0][srow0*HBK + sw0] = r[4];
        *(uint4*)&sB[buf][0][srow1*HBK + sw1] = r[5];
        *(uint4*)&sB[buf][1][srow0*HBK + sw0] = r[6];
        *(uint4*)&sB[buf][1][srow1*HBK + sw1] = r[7];
    };

    // prologue: kt=0 staged to buf 0, kt=1 loads in flight
    loadregs(0);
    stores(0);
    if (KT > 1) loadregs(1);
    int cur = 0;
    for (int kt = 0; kt < KT; kt++) {
        __syncthreads();                       // buf[cur] ready; prior reads of buf[cur^1] done
        if (kt+1 < KT) stores(cur^1);          // consumes loads issued one iteration ago
        if (kt+2 < KT) loadregs(kt+2);         // issue next; consumed next iteration
        short8v fAh[4], fAl[4], fBh[4], fBl[4];
        #pragma unroll
        for (int f = 0; f < 4; f++) {
            int ra = wm*64 + f*16 + lr, ua = (lk ^ (ra & 3))*8;
            fAh[f] = *(const short8v*)&sA[cur][0][ra*HBK + ua];
            fAl[f] = *(const short8v*)&sA[cur][1][ra*HBK + ua];
            int rb = wn*64 + f*16 + lr, ub = (lk ^ (rb & 3))*8;
            fBh[f] = *(const short8v*)&sB[cur][0][rb*HBK + ub];
            fBl[f] = *(const short8v*)&sB[cur][1][rb*HBK + ub];
        }
        #pragma unroll
        for (int i = 0; i < 4; i++)
            #pragma unroll
            for (int j = 0; j < 4; j++) {
                acc[i][j] = __builtin_amdgcn_mfma_f32_16x16x32_bf16(fAh[i], fBh[j], acc[i][j], 0, 0, 0);
                acc[i][j] = __builtin_amdgcn_mfma_f32_16x16x32_bf16(fAl[i], fBh[j], acc[i][j], 0, 0, 0);
                acc[i][j] = __builtin_amdgcn_mfma_f32_16x16x32_bf16(fAh[i], fBl[j], acc[i][j], 0, 0, 0);
            }
        cur ^= 1;
    }
    #pragma unroll
    for (int i = 0; i < 4; i++) {
        int m0 = bm + wm*64 + i*16 + lk*4;
        #pragma unroll
        for (int j = 0; j < 4; j++) {
            int n0 = bn + wn*64 + j*16 + lr;
            float bv = bias[n0];
            #pragma unroll
            for (int q = 0; q < 4; q++)
                C[(size_t)(m0+q)*N + n0] = acc[i][j][q] + bv;
        }
    }
}

// ---------------- persistent LSTM layer (r12 structure, best measured) ----------
__global__ __launch_bounds__(512, 2) void k_lstm_layer(
    const float* __restrict__ zxcat,
    const float* __restrict__ Whh_f, const float* __restrict__ Whh_b,
    unsigned short* __restrict__ h_hi, unsigned short* __restrict__ h_lo,
    unsigned* __restrict__ hbf, unsigned* __restrict__ flags)
{
    int chunk = blockIdx.x;        // 0..15 (32 hidden units each)
    int dir   = blockIdx.y;
    int tid = threadIdx.x;
    int wv = tid >> 6, l = tid & 63;
    int g  = wv & 3;               // gate
    int ks = wv >> 2;              // K-half (0/1)
    int lr = l & 15, lk = l >> 4;
    const float* zx  = zxcat + dir*NG4;
    const float* Whh = dir ? Whh_b : Whh_f;
    unsigned* hb = hbf + (size_t)dir * (2*NB*NH);
    unsigned* flag = flags + (size_t)dir * NCHUNK * 16;

    short8v bwh[2][8], bwl[2][8];
    #pragma unroll
    for (int uh = 0; uh < 2; uh++) {
        const float* wrow = Whh + ((size_t)(g*NH + chunk*32 + uh*16 + lr))*NH + ks*256 + lk*8;
        #pragma unroll
        for (int kt = 0; kt < 8; kt++) {
            float u[8];
            *(float4*)&u[0] = *(const float4*)(wrow + kt*32);
            *(float4*)&u[4] = *(const float4*)(wrow + kt*32 + 4);
            short8v sh, sl;
            #pragma unroll
            for (int j = 0; j < 8; j++) {
                short hi = f2bf(u[j]);
                sh[j] = hi;
                sl[j] = f2bf(u[j] - bf2f(hi));
            }
            bwh[uh][kt] = sh; bwl[uh][kt] = sl;
        }
    }

    __shared__ unsigned hstage[32*516];
    __shared__ float zsh[2][4][32][33];
    float c0 = 0.f, c1 = 0.f;

    for (int t = 0; t < NS; t++) {
        int t_eff = dir ? (NS-1-t) : t;

        float pz[2][4];
        #pragma unroll
        for (int cc = 0; cc < 2; cc++) {
            int cell = tid + cc*512, b = cell >> 5, u = cell & 31;
            const float* zr = zx + ((size_t)(b*NS + t_eff))*NGS + chunk*32 + u;
            #pragma unroll
            for (int g2 = 0; g2 < 4; g2++) pz[cc][g2] = zr[g2*NH];
        }

        if (t > 0) {
            {
                const unsigned* fp = &flag[(l & 15)*16];
                unsigned v;
                do { v = ld_sc1(fp); } while (!__all((int)(v >= (unsigned)t)));
                asm volatile("" ::: "memory");
            }
            const unsigned* hp = hb + ((t-1)&1)*(NB*NH);
            unsigned sv[32];
            #pragma unroll
            for (int i = 0; i < 32; i++) sv[i] = ld_sc1(hp + i*512 + tid);
            #pragma unroll
            for (int i = 0; i < 32; i++) hstage[i*516 + tid] = sv[i];
        }
        __syncthreads();   // barrier A: stage visible

        f32x4 acc[2][2][3];
        #pragma unroll
        for (int bh = 0; bh < 2; bh++)
            #pragma unroll
            for (int uh = 0; uh < 2; uh++)
                #pragma unroll
                for (int q = 0; q < 3; q++) acc[bh][uh][q] = (f32x4){0.f,0.f,0.f,0.f};
        if (t > 0) {
            #pragma unroll
            for (int kt = 0; kt < 8; kt++) {
                short8v ah[2], al[2];
                #pragma unroll
                for (int bh = 0; bh < 2; bh++) {
                    unsigned w8[8];
                    const unsigned* sp = hstage + (bh*16+lr)*516 + ks*256 + kt*32 + lk*8;
                    *(uint4*)&w8[0] = *(const uint4*)sp;
                    *(uint4*)&w8[4] = *(const uint4*)(sp+4);
                    unpack8(w8, ah[bh], al[bh]);
                }
                #pragma unroll
                for (int bh = 0; bh < 2; bh++)
                    #pragma unroll
                    for (int uh = 0; uh < 2; uh++) {
                        acc[bh][uh][0] = __builtin_amdgcn_mfma_f32_16x16x32_bf16(ah[bh], bwh[uh][kt], acc[bh][uh][0], 0, 0, 0);
                        acc[bh][uh][1] = __builtin_amdgcn_mfma_f32_16x16x32_bf16(al[bh], bwh[uh][kt], acc[bh][uh][1], 0, 0, 0);
                        acc[bh][uh][2] = __builtin_amdgcn_mfma_f32_16x16x32_bf16(ah[bh], bwl[uh][kt], acc[bh][uh][2], 0, 0, 0);
                    }
            }
        }
        #pragma unroll
        for (int bh = 0; bh < 2; bh++)
            #pragma unroll
            for (int uh = 0; uh < 2; uh++)
                #pragma unroll
                for (int j = 0; j < 4; j++)
                    zsh[ks][g][bh*16 + lk*4 + j][uh*16 + lr] =
                        acc[bh][uh][0][j] + acc[bh][uh][1][j] + acc[bh][uh][2][j];
        __syncthreads();   // barrier B: zsh ready

        unsigned hq0 = 0, hq1 = 0;
        #pragma unroll
        for (int cc = 0; cc < 2; cc++) {
            int cell = tid + cc*512, b = cell >> 5, u = cell & 31;
            float zi = pz[cc][0] + zsh[0][0][b][u] + zsh[1][0][b][u];
            float zf = pz[cc][1] + zsh[0][1][b][u] + zsh[1][1][b][u];
            float zg = pz[cc][2] + zsh[0][2][b][u] + zsh[1][2][b][u];
            float zo = pz[cc][3] + zsh[0][3][b][u] + zsh[1][3][b][u];
            float cold = cc ? c1 : c0;
            float cn = sigmoidf_(zf)*cold + sigmoidf_(zi)*tanhf(zg);
            float hn = sigmoidf_(zo)*tanhf(cn);
            unsigned pk = packbf3(hn);
            if (cc) { c1 = cn; hq1 = pk; } else { c0 = cn; hq0 = pk; }
            st_sc1(&hb[(size_t)(t&1)*(NB*NH) + b*NH + chunk*32 + u], pk);
        }
        __syncthreads();   // barrier C: all waves' stores drained
        if (tid == 0)
            st_sc1(&flag[chunk*16], (unsigned)(t+1));
        #pragma unroll
        for (int cc = 0; cc < 2; cc++) {
            int cell = tid + cc*512, b = cell >> 5, u = cell & 31;
            unsigned pk = cc ? hq1 : hq0;
            size_t o = ((size_t)(b*NS + t_eff))*NIN1 + dir*NH + chunk*32 + u;
            h_hi[o] = (unsigned short)(pk >> 16);
            h_lo[o] = (unsigned short)(pk & 0xFFFFu);
        }
    }
}

// ---------------- emissions: em = hid1 @ lin2W^T + b2 ----------------
__global__ __launch_bounds__(256) void k_lin2(const float* __restrict__ hid,
    const float* __restrict__ W2, const float* __restrict__ b2, float* __restrict__ em)
{
    int flat = blockIdx.x*256 + threadIdx.x;
    if (flat >= NBS*NT) return;
    int m = flat / NT, j = flat % NT;
    const float* hr = hid + (size_t)m*NHID;
    const float* wr = W2 + j*NHID;
    float acc = b2[j];
    #pragma unroll 8
    for (int k = 0; k < NHID; k += 4) {
        float4 h4 = *(const float4*)(hr+k);
        float4 w4 = *(const float4*)(wr+k);
        acc += h4.x*w4.x + h4.y*w4.y + h4.z*w4.z + h4.w*w4.w;
    }
    em[flat] = acc;
}

// ---------------- viterbi decode (one wave per batch item) ----------------
__global__ __launch_bounds__(64) void k_viterbi(const float* __restrict__ em,
    const float* __restrict__ start, const float* __restrict__ endv,
    const float* __restrict__ trans, float* __restrict__ dec)
{
    __shared__ float sc[NT];
    __shared__ float tr[NT][NT];
    __shared__ unsigned char hist[NS][NT];
    int b = blockIdx.x, tid = threadIdx.x;
    for (int i = tid; i < NT*NT; i += 64) tr[i/NT][i%NT] = trans[i];
    if (tid < NT) sc[tid] = start[tid] + em[((size_t)b*NS)*NT + tid];
    __syncthreads();
    for (int t = 1; t < NS; t++) {
        float best = -1e30f; int bi = 0;
        if (tid < NT) {
            for (int i = 0; i < NT; i++) {
                float v = sc[i] + tr[i][tid];
                if (v > best) { best = v; bi = i; }
            }
            hist[t][tid] = (unsigned char)bi;
            best += em[((size_t)b*NS + t)*NT + tid];
        }
        __syncthreads();
        if (tid < NT) sc[tid] = best;
        __syncthreads();
    }
    if (tid == 0) {
        float bv = sc[0] + endv[0]; int tag = 0;
        for (int j = 1; j < NT; j++) { float v = sc[j] + endv[j]; if (v > bv) { bv = v; tag = j; } }
        dec[b*NS + NS-1] = (float)tag;
        for (int t = NS-1; t >= 1; t--) { tag = hist[t][tag]; dec[b*NS + t-1] = (float)tag; }
    }
}

// ---------------- CRF NLL (mask is all ones) ----------------
__global__ __launch_bounds__(64) void k_nll(const float* __restrict__ em,
    const int* __restrict__ tags, const float* __restrict__ start,
    const float* __restrict__ endv, const float* __restrict__ trans,
    float* __restrict__ partial)
{
    __shared__ float sc[NT];
    __shared__ float tr[NT][NT];
    int b = blockIdx.x, tid = threadIdx.x;
    for (int i = tid; i < NT*NT; i += 64) tr[i/NT][i%NT] = trans[i];
    if (tid < NT) sc[tid] = start[tid] + em[((size_t)b*NS)*NT + tid];
    __syncthreads();
    for (int t = 1; t < NS; t++) {
        float nv = 0.f;
        if (tid < NT) {
            float m = -1e30f;
            for (int i = 0; i < NT; i++) m = fmaxf(m, sc[i] + tr[i][tid]);
            float s = 0.f;
            for (int i = 0; i < NT; i++) s += expf(sc[i] + tr[i][tid] - m);
            nv = m + logf(s) + em[((size_t)b*NS + t)*NT + tid];
        }
        __syncthreads();
        if (tid < NT) sc[tid] = nv;
        __syncthreads();
    }
    if (tid == 0) {
        float m = -1e30f;
        for (int j = 0; j < NT; j++) m = fmaxf(m, sc[j] + endv[j]);
        float s = 0.f;
        for (int j = 0; j < NT; j++) s += expf(sc[j] + endv[j] - m);
        float logZ = m + logf(s);
        const int* tg = tags + b*NS;
        float num = start[tg[0]] + em[((size_t)b*NS)*NT + tg[0]];
        for (int t = 1; t < NS; t++)
            num += tr[tg[t-1]][tg[t]] + em[((size_t)b*NS + t)*NT + tg[t]];
        num += endv[tg[NS-1]];
        partial[b] = -(num - logZ);
    }
}

__global__ void k_loss_final(const float* __restrict__ partial, float* __restrict__ loss)
{
    if (threadIdx.x == 0 && blockIdx.x == 0) {
        float s = 0.f;
        for (int b = 0; b < NB; b++) s += partial[b];
        *loss = s / (float)(NB*NS);
    }
}

extern "C" void kernel_launch(void* const* d_in, const int* in_sizes, int n_in,
                              void* d_out, int out_size, void* d_ws, size_t ws_size,
                              hipStream_t stream)
{
    const int*   x_word = (const int*)d_in[0];
    const float* x_pos  = (const float*)d_in[1];
    const int*   x_char = (const int*)d_in[2];
    const float* x_enr  = (const float*)d_in[3];
    const int*   y_word = (const int*)d_in[5];
    const float* wembW  = (const float*)d_in[6];
    const float* cembW  = (const float*)d_in[7];
    const float* cnnW   = (const float*)d_in[8];
    const float* cnnb   = (const float*)d_in[9];
    const float* lin1W  = (const float*)d_in[10];
    const float* lin1b  = (const float*)d_in[11];
    const float* lin2W  = (const float*)d_in[12];
    const float* lin2b  = (const float*)d_in[13];
    const float* crf_s  = (const float*)d_in[14];
    const float* crf_e  = (const float*)d_in[15];
    const float* crf_tr = (const float*)d_in[16];
    const float* l0f_Wih = (const float*)d_in[17];
    const float* l0f_Whh = (const float*)d_in[18];
    const float* l0f_b   = (const float*)d_in[19];
    const float* l0b_Wih = (const float*)d_in[20];
    const float* l0b_Whh = (const float*)d_in[21];
    const float* l0b_b   = (const float*)d_in[22];
    const float* l1f_Wih = (const float*)d_in[23];
    const float* l1f_Whh = (const float*)d_in[24];
    const float* l1f_b   = (const float*)d_in[25];
    const float* l1b_Wih = (const float*)d_in[26];
    const float* l1b_Whh = (const float*)d_in[27];
    const float* l1b_b   = (const float*)d_in[28];

    char* wsb = (char*)d_ws;
    size_t off = 0;
    auto alloc = [&](size_t bytes) { char* p = wsb + off; off += (bytes + 255) & ~(size_t)255; return p; };
    unsigned short* xh  = (unsigned short*)alloc((size_t)NBS*NIN0P*2);
    unsigned short* xl  = (unsigned short*)alloc((size_t)NBS*NIN0P*2);
    unsigned short* w0h = (unsigned short*)alloc((size_t)NGS*NIN0P*2);
    unsigned short* w0l = (unsigned short*)alloc((size_t)NGS*NIN0P*2);
    unsigned short* w1h = (unsigned short*)alloc((size_t)NGS*NIN1*2);
    unsigned short* w1l = (unsigned short*)alloc((size_t)NGS*NIN1*2);
    unsigned short* wlh = (unsigned short*)alloc((size_t)NHID*NIN1*2);
    unsigned short* wll = (unsigned short*)alloc((size_t)NHID*NIN1*2);
    float*    zxcat = (float*)alloc((size_t)NBS*NGS*4);
    unsigned short* h0h = (unsigned short*)alloc((size_t)NBS*NIN1*2);
    unsigned short* h0l = (unsigned short*)alloc((size_t)NBS*NIN1*2);
    unsigned short* h1h = (unsigned short*)alloc((size_t)NBS*NIN1*2);
    unsigned short* h1l = (unsigned short*)alloc((size_t)NBS*NIN1*2);
    float*    hid1  = (float*)alloc((size_t)NBS*NHID*4);
    float*    partial = (float*)alloc(256);
    float*    bias0 = (float*)alloc((size_t)NGS*4);
    float*    bias1 = (float*)alloc((size_t)NGS*4);
    unsigned* hbf   = (unsigned*)alloc((size_t)2*2*NB*NH*4);
    unsigned* flags = (unsigned*)alloc((size_t)2*NCHUNK*16*4);

    float* em_out   = (float*)d_out;
    float* dec_out  = em_out + (size_t)NBS*NT;
    float* loss_out = dec_out + NBS;

    // 1. pack weights into hi/lo planes (cat fwd|bwd rows)
    k_pack_w<<<(NG4*NIN0P+255)/256, 256, 0, stream>>>(l0f_Wih, w0h, w0l, NG4, NIN0, NIN0P);
    k_pack_w<<<(NG4*NIN0P+255)/256, 256, 0, stream>>>(l0b_Wih, w0h + (size_t)NG4*NIN0P, w0l + (size_t)NG4*NIN0P, NG4, NIN0, NIN0P);
    k_pack_w<<<(NG4*NIN1+255)/256, 256, 0, stream>>>(l1f_Wih, w1h, w1l, NG4, NIN1, NIN1);
    k_pack_w<<<(NG4*NIN1+255)/256, 256, 0, stream>>>(l1b_Wih, w1h + (size_t)NG4*NIN1, w1l + (size_t)NG4*NIN1, NG4, NIN1, NIN1);
    k_pack_w<<<(NHID*NIN1+255)/256, 256, 0, stream>>>(lin1W, wlh, wll, NHID, NIN1, NIN1);
    // cat biases
    hipMemcpyAsync(bias0,       l0f_b, NG4*4, hipMemcpyDeviceToDevice, stream);
    hipMemcpyAsync(bias0 + NG4, l0b_b, NG4*4, hipMemcpyDeviceToDevice, stream);
    hipMemcpyAsync(bias1,       l1f_b, NG4*4, hipMemcpyDeviceToDevice, stream);
    hipMemcpyAsync(bias1 + NG4, l1b_b, NG4*4, hipMemcpyDeviceToDevice, stream);
    // 2. features (hi/lo planes)
    k_features<<<NBS, 128, 0, stream>>>(x_word, x_pos, x_char, x_enr, wembW, cembW, cnnW, cnnb, xh, xl);
    // 3. layer-0 fused input projection (both dirs, N=4096)
    k_gemm_hl<<<dim3(NBS/128, NGS/128), 256, 0, stream>>>(xh, xl, w0h, w0l, bias0, zxcat, NBS, NGS, NIN0P);
    // 4. layer-0 recurrence
    hipMemsetAsync(flags, 0, (size_t)2*NCHUNK*16*4, stream);
    k_lstm_layer<<<dim3(NCHUNK, 2), 512, 0, stream>>>(zxcat, l0f_Whh, l0b_Whh, h0h, h0l, hbf, flags);
    // 5. layer-1 fused input projection
    k_gemm_hl<<<dim3(NBS/128, NGS/128), 256, 0, stream>>>(h0h, h0l, w1h, w1l, bias1, zxcat, NBS, NGS, NIN1);
    // 6. layer-1 recurrence
    hipMemsetAsync(flags, 0, (size_t)2*NCHUNK*16*4, stream);
    k_lstm_layer<<<dim3(NCHUNK, 2), 512, 0, stream>>>(zxcat, l1f_Whh, l1b_Whh, h1h, h1l, hbf, flags);
    // 7. head
    k_gemm_hl<<<dim3(NBS/128, NHID/128), 256, 0, stream>>>(h1h, h1l, wlh, wll, lin1b, hid1, NBS, NHID, NIN1);
    k_lin2<<<(NBS*NT+255)/256, 256, 0, stream>>>(hid1, lin2W, lin2b, em_out);
    // 8. CRF
    k_viterbi<<<NB, 64, 0, stream>>>(em_out, crf_s, crf_e, crf_tr, dec_out);
    k_nll<<<NB, 64, 0, stream>>>(em_out, y_word, crf_s, crf_e, crf_tr, partial);
    k_loss_final<<<1, 64, 0, stream>>>(partial, loss_out);
}

// Round 14
// 4233.704 us; speedup vs baseline: 1.5175x; 1.0662x over previous
//
#include <hip/hip_runtime.h>
#include <hip/hip_bf16.h>
#include <math.h>

// ---- problem dims ----
constexpr int NB   = 32;
constexpr int NS   = 256;
constexpr int NLC  = 16;
constexpr int NWD  = 256;
constexpr int NCD  = 124;
constexpr int NCO  = 32;
constexpr int NPOS = 36;
constexpr int NENR = 7;
constexpr int NH   = 512;
constexpr int NT   = 18;
constexpr int NIN0 = 331;
constexpr int NIN0P= 352;    // padded to x32
constexpr int NIN1 = 1024;
constexpr int NBS  = NB*NS;  // 8192
constexpr int NG4  = 4*NH;   // 2048
constexpr int NGS  = 4096;   // fused zx row stride (fwd 2048 | bwd 2048)
constexpr int NHID = 128;
constexpr int NCHUNK = 16;   // unit-chunks per dir (32 units each)

typedef __attribute__((ext_vector_type(8))) short short8v;
typedef __attribute__((ext_vector_type(4))) float f32x4;

__device__ __forceinline__ float sigmoidf_(float x){ return 1.0f/(1.0f+expf(-x)); }
__device__ __forceinline__ short f2bf(float f) {
    union { __hip_bfloat16 h; short s; } u;
    u.h = __float2bfloat16(f);
    return u.s;
}
__device__ __forceinline__ float bf2f(short s) {
    union { unsigned u; float f; } v;
    v.u = ((unsigned)(unsigned short)s) << 16;
    return v.f;
}
__device__ __forceinline__ unsigned packbf3(float v) {
    short hi = f2bf(v);
    short lo = f2bf(v - bf2f(hi));
    return ((unsigned)(unsigned short)hi << 16) | (unsigned short)lo;
}
// 8 packed u32 -> hi/lo bf16 fragments (lstm exchange path only)
__device__ __forceinline__ void unpack8(const unsigned* w, short8v& hi, short8v& lo) {
    union U { short8v s; unsigned u[4]; } H, L;
    #pragma unroll
    for (int i = 0; i < 4; i++) {
        H.u[i] = (w[2*i+1] & 0xFFFF0000u) | (w[2*i] >> 16);
        L.u[i] = (w[2*i+1] << 16) | (w[2*i] & 0xFFFFu);
    }
    hi = H.s; lo = L.s;
}
// relaxed agent-scope ops (sc1 path, no cache maintenance) — proven in r6
__device__ __forceinline__ unsigned ld_sc1(const unsigned* p) {
    return __hip_atomic_load(p, __ATOMIC_RELAXED, __HIP_MEMORY_SCOPE_AGENT);
}
__device__ __forceinline__ void st_sc1(unsigned* p, unsigned v) {
    __hip_atomic_store(p, v, __ATOMIC_RELAXED, __HIP_MEMORY_SCOPE_AGENT);
}

// -------- features: word embed + char CNN + concat + relu -> hi/lo bf16 planes ----
// r14: cnnW staged TRANSPOSED in LDS (two 62-column halves, f32) ->
// ce reads broadcast (same addr across lanes), wT reads 32 distinct banks.
// Replaces the per-lane scattered global gathers of cnnW (~2.4G 4B reads).
__global__ __launch_bounds__(128) void k_features(const int* __restrict__ x_word,
    const float* __restrict__ x_pos, const int* __restrict__ x_char,
    const float* __restrict__ x_enr, const float* __restrict__ wembW,
    const float* __restrict__ cembW, const float* __restrict__ cnnW,
    const float* __restrict__ cnnb,
    unsigned short* __restrict__ xh, unsigned short* __restrict__ xl)
{
    __shared__ float ce[NLC][NCD];     // 7.9 KB
    __shared__ float wT[310*33];       // 40.9 KB: half of cnnW, [ck][o] padded
    __shared__ float cv[NCO][14];
    __shared__ float cpool[NCO];
    int n = blockIdx.x;
    int tid = threadIdx.x;
    for (int i = tid; i < NLC*NCD; i += 128) {
        int l = i / NCD, c = i % NCD;
        ce[l][c] = cembW[x_char[n*NLC + l]*NCD + c];
    }
    float acc3[3] = {0.f, 0.f, 0.f};   // tasks p=tid, tid+128, tid+256
    #pragma unroll
    for (int half = 0; half < 2; half++) {
        int csta = half*62;            // 62 + 62 = 124 columns
        __syncthreads();               // protect wT from previous pass reads (+ce pass0)
        for (int i = tid; i < 310*32; i += 128) {
            int o = i / 310, ck = i - o*310;            // coalesced cnnW read
            wT[ck*33 + o] = cnnW[o*(NCD*5) + csta*5 + ck];
        }
        __syncthreads();
        #pragma unroll
        for (int q = 0; q < 3; q++) {
            int p = tid + q*128;
            int o = p & 31, t = p >> 5;                 // t in 0..11
            float acc = acc3[q];
            for (int c = 0; c < 62; c++) {
                #pragma unroll
                for (int k = 0; k < 5; k++)
                    acc += ce[t+k][csta + c] * wT[(c*5+k)*33 + o];
            }
            acc3[q] = acc;
        }
    }
    #pragma unroll
    for (int q = 0; q < 3; q++) {
        int p = tid + q*128;
        cv[p & 31][p >> 5] = acc3[q];
    }
    __syncthreads();
    if (tid < NCO) {
        float m = cv[tid][0];
        #pragma unroll
        for (int t = 1; t < 12; t++) m = fmaxf(m, cv[tid][t]);
        cpool[tid] = m + cnnb[tid];
    }
    __syncthreads();
    int widx = x_word[n];
    for (int j = tid; j < NIN0P; j += 128) {
        float v;
        if (j < NWD)            v = wembW[(size_t)widx*NWD + j];
        else if (j < NWD+NPOS)  v = x_pos[n*NPOS + (j-NWD)];
        else if (j < NWD+NPOS+NCO) v = cpool[j-(NWD+NPOS)];
        else if (j < NIN0)      v = x_enr[n*NENR + (j-(NWD+NPOS+NCO))];
        else                    v = 0.f;
        v = fmaxf(v, 0.f);
        short hi = f2bf(v);
        xh[(size_t)n*NIN0P + j] = (unsigned short)hi;
        xl[(size_t)n*NIN0P + j] = (unsigned short)f2bf(v - bf2f(hi));
    }
}

// -------- pack f32 weight [N][Ksrc] -> hi/lo bf16 planes [N][Kdst] (zero pad) ----
__global__ void k_pack_w(const float* __restrict__ W,
                         unsigned short* __restrict__ Wh, unsigned short* __restrict__ Wl,
                         int N, int Ksrc, int Kdst)
{
    int idx = blockIdx.x*256 + threadIdx.x;
    if (idx >= N*Kdst) return;
    int n = idx / Kdst, k = idx % Kdst;
    float v = (k < Ksrc) ? W[(size_t)n*Ksrc + k] : 0.f;
    short hi = f2bf(v);
    Wh[idx] = (unsigned short)hi;
    Wl[idx] = (unsigned short)f2bf(v - bf2f(hi));
}

// -------- split-plane bf16x3 MFMA GEMM: C[M,N] = A@W^T + bias ----------------
// r13 structure + r14: 4x4 supertile blockIdx swizzle (identity when grid
// not 4-divisible) for L2/L3 panel reuse.
constexpr int HBK = 32;
__global__ __launch_bounds__(256, 2) void k_gemm_hl(
    const unsigned short* __restrict__ Ah, const unsigned short* __restrict__ Al,
    const unsigned short* __restrict__ Bh, const unsigned short* __restrict__ Bl,
    const float* __restrict__ bias, float* __restrict__ C,
    int M, int N, int K)
{
    __shared__ unsigned short sA[2][2][128*HBK];   // [buf][hi/lo] 32 KB
    __shared__ unsigned short sB[2][2][128*HBK];   // 32 KB
    int bx = blockIdx.x, by = blockIdx.y;
    {
        int nMb = gridDim.x, nNb = gridDim.y;
        if (((nMb | nNb) & 3) == 0) {
            int lin = by * nMb + bx;
            int sid = lin >> 4, rem = lin & 15;
            int spr = nNb >> 2;
            int sm = sid / spr, sn = sid - sm*spr;
            bx = sm*4 + (rem >> 2);
            by = sn*4 + (rem & 3);
        }
    }
    int bm = bx*128, bn = by*128;
    int tid = threadIdx.x;
    int l = tid & 63, wv = tid >> 6;
    int wm = wv >> 1, wn = wv & 1;
    int lr = l & 15, lk = l >> 4;

    f32x4 acc[4][4];
    #pragma unroll
    for (int i = 0; i < 4; i++)
        #pragma unroll
        for (int j = 0; j < 4; j++) acc[i][j] = (f32x4){0.f,0.f,0.f,0.f};

    int KT = K / HBK;
    uint4 r[8];
    int srow0 = tid >> 2, su0 = tid & 3;
    int srow1 = (256 + tid) >> 2, su1 = tid & 3;

    auto loadregs = [&](int kt) {
        size_t ca = (size_t)kt*HBK;
        r[0] = *(const uint4*)(Ah + (size_t)(bm+srow0)*K + ca + su0*8);
        r[1] = *(const uint4*)(Ah + (size_t)(bm+srow1)*K + ca + su1*8);
        r[2] = *(const uint4*)(Al + (size_t)(bm+srow0)*K + ca + su0*8);
        r[3] = *(const uint4*)(Al + (size_t)(bm+srow1)*K + ca + su1*8);
        r[4] = *(const uint4*)(Bh + (size_t)(bn+srow0)*K + ca + su0*8);
        r[5] = *(const uint4*)(Bh + (size_t)(bn+srow1)*K + ca + su1*8);
        r[6] = *(const uint4*)(Bl + (size_t)(bn+srow0)*K + ca + su0*8);
        r[7] = *(const uint4*)(Bl + (size_t)(bn+srow1)*K + ca + su1*8);
    };
    auto stores = [&](int buf) {
        int sw0 = (su0 ^ (srow0 & 3))*8, sw1 = (su1 ^ (srow1 & 3))*8;
        *(uint4*)&sA[buf][0][srow0*HBK + sw0] = r[0];
        *(uint4*)&sA[buf][0][srow1*HBK + sw1] = r[1];
        *(uint4*)&sA[buf][1][srow0*HBK + sw0] = r[2];
        *(uint4*)&sA[buf][1][srow1*HBK + sw1] = r[3];
        *(uint4*)&sB[buf][0][srow0*HBK + sw0] = r[4];
        *(uint4*)&sB[buf][0][srow1*HBK + sw1] = r[5];
        *(uint4*)&sB[buf][1][srow0*HBK + sw0] = r[6];
        *(uint4*)&sB[buf][1][srow1*HBK + sw1] = r[7];
    };

    loadregs(0);
    stores(0);
    if (KT > 1) loadregs(1);
    int cur = 0;
    for (int kt = 0; kt < KT; kt++) {
        __syncthreads();
        if (kt+1 < KT) stores(cur^1);
        if (kt+2 < KT) loadregs(kt+2);
        short8v fAh[4], fAl[4], fBh[4], fBl[4];
        #pragma unroll
        for (int f = 0; f < 4; f++) {
            int ra = wm*64 + f*16 + lr, ua = (lk ^ (ra & 3))*8;
            fAh[f] = *(const short8v*)&sA[cur][0][ra*HBK + ua];
            fAl[f] = *(const short8v*)&sA[cur][1][ra*HBK + ua];
            int rb = wn*64 + f*16 + lr, ub = (lk ^ (rb & 3))*8;
            fBh[f] = *(const short8v*)&sB[cur][0][rb*HBK + ub];
            fBl[f] = *(const short8v*)&sB[cur][1][rb*HBK + ub];
        }
        #pragma unroll
        for (int i = 0; i < 4; i++)
            #pragma unroll
            for (int j = 0; j < 4; j++) {
                acc[i][j] = __builtin_amdgcn_mfma_f32_16x16x32_bf16(fAh[i], fBh[j], acc[i][j], 0, 0, 0);
                acc[i][j] = __builtin_amdgcn_mfma_f32_16x16x32_bf16(fAl[i], fBh[j], acc[i][j], 0, 0, 0);
                acc[i][j] = __builtin_amdgcn_mfma_f32_16x16x32_bf16(fAh[i], fBl[j], acc[i][j], 0, 0, 0);
            }
        cur ^= 1;
    }
    #pragma unroll
    for (int i = 0; i < 4; i++) {
        int m0 = bm + wm*64 + i*16 + lk*4;
        #pragma unroll
        for (int j = 0; j < 4; j++) {
            int n0 = bn + wn*64 + j*16 + lr;
            float bv = bias[n0];
            #pragma unroll
            for (int q = 0; q < 4; q++)
                C[(size_t)(m0+q)*N + n0] = acc[i][j][q] + bv;
        }
    }
}

// ---------------- persistent LSTM layer (r12 structure, best measured) ----------
__global__ __launch_bounds__(512, 2) void k_lstm_layer(
    const float* __restrict__ zxcat,
    const float* __restrict__ Whh_f, const float* __restrict__ Whh_b,
    unsigned short* __restrict__ h_hi, unsigned short* __restrict__ h_lo,
    unsigned* __restrict__ hbf, unsigned* __restrict__ flags)
{
    int chunk = blockIdx.x;
    int dir   = blockIdx.y;
    int tid = threadIdx.x;
    int wv = tid >> 6, l = tid & 63;
    int g  = wv & 3;
    int ks = wv >> 2;
    int lr = l & 15, lk = l >> 4;
    const float* zx  = zxcat + dir*NG4;
    const float* Whh = dir ? Whh_b : Whh_f;
    unsigned* hb = hbf + (size_t)dir * (2*NB*NH);
    unsigned* flag = flags + (size_t)dir * NCHUNK * 16;

    short8v bwh[2][8], bwl[2][8];
    #pragma unroll
    for (int uh = 0; uh < 2; uh++) {
        const float* wrow = Whh + ((size_t)(g*NH + chunk*32 + uh*16 + lr))*NH + ks*256 + lk*8;
        #pragma unroll
        for (int kt = 0; kt < 8; kt++) {
            float u[8];
            *(float4*)&u[0] = *(const float4*)(wrow + kt*32);
            *(float4*)&u[4] = *(const float4*)(wrow + kt*32 + 4);
            short8v sh, sl;
            #pragma unroll
            for (int j = 0; j < 8; j++) {
                short hi = f2bf(u[j]);
                sh[j] = hi;
                sl[j] = f2bf(u[j] - bf2f(hi));
            }
            bwh[uh][kt] = sh; bwl[uh][kt] = sl;
        }
    }

    __shared__ unsigned hstage[32*516];
    __shared__ float zsh[2][4][32][33];
    float c0 = 0.f, c1 = 0.f;

    for (int t = 0; t < NS; t++) {
        int t_eff = dir ? (NS-1-t) : t;

        float pz[2][4];
        #pragma unroll
        for (int cc = 0; cc < 2; cc++) {
            int cell = tid + cc*512, b = cell >> 5, u = cell & 31;
            const float* zr = zx + ((size_t)(b*NS + t_eff))*NGS + chunk*32 + u;
            #pragma unroll
            for (int g2 = 0; g2 < 4; g2++) pz[cc][g2] = zr[g2*NH];
        }

        if (t > 0) {
            {
                const unsigned* fp = &flag[(l & 15)*16];
                unsigned v;
                do { v = ld_sc1(fp); } while (!__all((int)(v >= (unsigned)t)));
                asm volatile("" ::: "memory");
            }
            const unsigned* hp = hb + ((t-1)&1)*(NB*NH);
            unsigned sv[32];
            #pragma unroll
            for (int i = 0; i < 32; i++) sv[i] = ld_sc1(hp + i*512 + tid);
            #pragma unroll
            for (int i = 0; i < 32; i++) hstage[i*516 + tid] = sv[i];
        }
        __syncthreads();   // barrier A: stage visible

        f32x4 acc[2][2][3];
        #pragma unroll
        for (int bh = 0; bh < 2; bh++)
            #pragma unroll
            for (int uh = 0; uh < 2; uh++)
                #pragma unroll
                for (int q = 0; q < 3; q++) acc[bh][uh][q] = (f32x4){0.f,0.f,0.f,0.f};
        if (t > 0) {
            #pragma unroll
            for (int kt = 0; kt < 8; kt++) {
                short8v ah[2], al[2];
                #pragma unroll
                for (int bh = 0; bh < 2; bh++) {
                    unsigned w8[8];
                    const unsigned* sp = hstage + (bh*16+lr)*516 + ks*256 + kt*32 + lk*8;
                    *(uint4*)&w8[0] = *(const uint4*)sp;
                    *(uint4*)&w8[4] = *(const uint4*)(sp+4);
                    unpack8(w8, ah[bh], al[bh]);
                }
                #pragma unroll
                for (int bh = 0; bh < 2; bh++)
                    #pragma unroll
                    for (int uh = 0; uh < 2; uh++) {
                        acc[bh][uh][0] = __builtin_amdgcn_mfma_f32_16x16x32_bf16(ah[bh], bwh[uh][kt], acc[bh][uh][0], 0, 0, 0);
                        acc[bh][uh][1] = __builtin_amdgcn_mfma_f32_16x16x32_bf16(al[bh], bwh[uh][kt], acc[bh][uh][1], 0, 0, 0);
                        acc[bh][uh][2] = __builtin_amdgcn_mfma_f32_16x16x32_bf16(ah[bh], bwl[uh][kt], acc[bh][uh][2], 0, 0, 0);
                    }
            }
        }
        #pragma unroll
        for (int bh = 0; bh < 2; bh++)
            #pragma unroll
            for (int uh = 0; uh < 2; uh++)
                #pragma unroll
                for (int j = 0; j < 4; j++)
                    zsh[ks][g][bh*16 + lk*4 + j][uh*16 + lr] =
                        acc[bh][uh][0][j] + acc[bh][uh][1][j] + acc[bh][uh][2][j];
        __syncthreads();   // barrier B: zsh ready

        unsigned hq0 = 0, hq1 = 0;
        #pragma unroll
        for (int cc = 0; cc < 2; cc++) {
            int cell = tid + cc*512, b = cell >> 5, u = cell & 31;
            float zi = pz[cc][0] + zsh[0][0][b][u] + zsh[1][0][b][u];
            float zf = pz[cc][1] + zsh[0][1][b][u] + zsh[1][1][b][u];
            float zg = pz[cc][2] + zsh[0][2][b][u] + zsh[1][2][b][u];
            float zo = pz[cc][3] + zsh[0][3][b][u] + zsh[1][3][b][u];
            float cold = cc ? c1 : c0;
            float cn = sigmoidf_(zf)*cold + sigmoidf_(zi)*tanhf(zg);
            float hn = sigmoidf_(zo)*tanhf(cn);
            unsigned pk = packbf3(hn);
            if (cc) { c1 = cn; hq1 = pk; } else { c0 = cn; hq0 = pk; }
            st_sc1(&hb[(size_t)(t&1)*(NB*NH) + b*NH + chunk*32 + u], pk);
        }
        __syncthreads();   // barrier C: all waves' stores drained
        if (tid == 0)
            st_sc1(&flag[chunk*16], (unsigned)(t+1));
        #pragma unroll
        for (int cc = 0; cc < 2; cc++) {
            int cell = tid + cc*512, b = cell >> 5, u = cell & 31;
            unsigned pk = cc ? hq1 : hq0;
            size_t o = ((size_t)(b*NS + t_eff))*NIN1 + dir*NH + chunk*32 + u;
            h_hi[o] = (unsigned short)(pk >> 16);
            h_lo[o] = (unsigned short)(pk & 0xFFFFu);
        }
    }
}

// ---------------- emissions: em = hid1 @ lin2W^T + b2 ----------------
__global__ __launch_bounds__(256) void k_lin2(const float* __restrict__ hid,
    const float* __restrict__ W2, const float* __restrict__ b2, float* __restrict__ em)
{
    int flat = blockIdx.x*256 + threadIdx.x;
    if (flat >= NBS*NT) return;
    int m = flat / NT, j = flat % NT;
    const float* hr = hid + (size_t)m*NHID;
    const float* wr = W2 + j*NHID;
    float acc = b2[j];
    #pragma unroll 8
    for (int k = 0; k < NHID; k += 4) {
        float4 h4 = *(const float4*)(hr+k);
        float4 w4 = *(const float4*)(wr+k);
        acc += h4.x*w4.x + h4.y*w4.y + h4.z*w4.z + h4.w*w4.w;
    }
    em[flat] = acc;
}

// ---------------- fused CRF: viterbi decode + NLL forward in one pass ---------
__global__ __launch_bounds__(64) void k_crf(const float* __restrict__ em,
    const int* __restrict__ tags, const float* __restrict__ start,
    const float* __restrict__ endv, const float* __restrict__ trans,
    float* __restrict__ dec, float* __restrict__ partial)
{
    __shared__ float tr[NT][NT];
    __shared__ float vsc[NT], nsc[NT];
    __shared__ unsigned char hist[NS][NT];
    __shared__ float numsh;
    int b = blockIdx.x, tid = threadIdx.x;
    for (int i = tid; i < NT*NT; i += 64) tr[i/NT][i%NT] = trans[i];
    if (tid < NT) {
        float e0 = em[((size_t)b*NS)*NT + tid];
        vsc[tid] = start[tid] + e0;
        nsc[tid] = start[tid] + e0;
    }
    __syncthreads();
    const int* tg = tags + b*NS;
    float num = 0.f;
    for (int t = 1; t < NS; t++) {
        float nv_v = 0.f, nv_n = 0.f;
        if (tid < NT) {
            float emv = em[((size_t)b*NS + t)*NT + tid];
            float best = -1e30f; int bi = 0;
            float m = -1e30f;
            for (int i = 0; i < NT; i++) {
                float v = vsc[i] + tr[i][tid];
                if (v > best) { best = v; bi = i; }   // strict > = first max
                m = fmaxf(m, nsc[i] + tr[i][tid]);
            }
            hist[t][tid] = (unsigned char)bi;
            nv_v = best + emv;
            float s = 0.f;
            for (int i = 0; i < NT; i++) s += expf(nsc[i] + tr[i][tid] - m);
            nv_n = m + logf(s) + emv;
        } else if (tid == 32) {
            num += tr[tg[t-1]][tg[t]] + em[((size_t)b*NS + t)*NT + tg[t]];
        }
        __syncthreads();
        if (tid < NT) { vsc[tid] = nv_v; nsc[tid] = nv_n; }
        __syncthreads();
    }
    if (tid == 32) numsh = num;
    __syncthreads();
    if (tid == 0) {
        // viterbi backtrack
        float bv = vsc[0] + endv[0]; int tag = 0;
        for (int j = 1; j < NT; j++) { float v = vsc[j] + endv[j]; if (v > bv) { bv = v; tag = j; } }
        dec[b*NS + NS-1] = (float)tag;
        for (int t = NS-1; t >= 1; t--) { tag = hist[t][tag]; dec[b*NS + t-1] = (float)tag; }
        // nll
        float m = -1e30f;
        for (int j = 0; j < NT; j++) m = fmaxf(m, nsc[j] + endv[j]);
        float s = 0.f;
        for (int j = 0; j < NT; j++) s += expf(nsc[j] + endv[j] - m);
        float logZ = m + logf(s);
        float numer = start[tg[0]] + em[((size_t)b*NS)*NT + tg[0]] + numsh + endv[tg[NS-1]];
        partial[b] = -(numer - logZ);
    }
}

__global__ void k_loss_final(const float* __restrict__ partial, float* __restrict__ loss)
{
    if (threadIdx.x == 0 && blockIdx.x == 0) {
        float s = 0.f;
        for (int b = 0; b < NB; b++) s += partial[b];
        *loss = s / (float)(NB*NS);
    }
}

extern "C" void kernel_launch(void* const* d_in, const int* in_sizes, int n_in,
                              void* d_out, int out_size, void* d_ws, size_t ws_size,
                              hipStream_t stream)
{
    const int*   x_word = (const int*)d_in[0];
    const float* x_pos  = (const float*)d_in[1];
    const int*   x_char = (const int*)d_in[2];
    const float* x_enr  = (const float*)d_in[3];
    const int*   y_word = (const int*)d_in[5];
    const float* wembW  = (const float*)d_in[6];
    const float* cembW  = (const float*)d_in[7];
    const float* cnnW   = (const float*)d_in[8];
    const float* cnnb   = (const float*)d_in[9];
    const float* lin1W  = (const float*)d_in[10];
    const float* lin1b  = (const float*)d_in[11];
    const float* lin2W  = (const float*)d_in[12];
    const float* lin2b  = (const float*)d_in[13];
    const float* crf_s  = (const float*)d_in[14];
    const float* crf_e  = (const float*)d_in[15];
    const float* crf_tr = (const float*)d_in[16];
    const float* l0f_Wih = (const float*)d_in[17];
    const float* l0f_Whh = (const float*)d_in[18];
    const float* l0f_b   = (const float*)d_in[19];
    const float* l0b_Wih = (const float*)d_in[20];
    const float* l0b_Whh = (const float*)d_in[21];
    const float* l0b_b   = (const float*)d_in[22];
    const float* l1f_Wih = (const float*)d_in[23];
    const float* l1f_Whh = (const float*)d_in[24];
    const float* l1f_b   = (const float*)d_in[25];
    const float* l1b_Wih = (const float*)d_in[26];
    const float* l1b_Whh = (const float*)d_in[27];
    const float* l1b_b   = (const float*)d_in[28];

    char* wsb = (char*)d_ws;
    size_t off = 0;
    auto alloc = [&](size_t bytes) { char* p = wsb + off; off += (bytes + 255) & ~(size_t)255; return p; };
    unsigned short* xh  = (unsigned short*)alloc((size_t)NBS*NIN0P*2);
    unsigned short* xl  = (unsigned short*)alloc((size_t)NBS*NIN0P*2);
    unsigned short* w0h = (unsigned short*)alloc((size_t)NGS*NIN0P*2);
    unsigned short* w0l = (unsigned short*)alloc((size_t)NGS*NIN0P*2);
    unsigned short* w1h = (unsigned short*)alloc((size_t)NGS*NIN1*2);
    unsigned short* w1l = (unsigned short*)alloc((size_t)NGS*NIN1*2);
    unsigned short* wlh = (unsigned short*)alloc((size_t)NHID*NIN1*2);
    unsigned short* wll = (unsigned short*)alloc((size_t)NHID*NIN1*2);
    float*    zxcat = (float*)alloc((size_t)NBS*NGS*4);
    unsigned short* h0h = (unsigned short*)alloc((size_t)NBS*NIN1*2);
    unsigned short* h0l = (unsigned short*)alloc((size_t)NBS*NIN1*2);
    unsigned short* h1h = (unsigned short*)alloc((size_t)NBS*NIN1*2);
    unsigned short* h1l = (unsigned short*)alloc((size_t)NBS*NIN1*2);
    float*    hid1  = (float*)alloc((size_t)NBS*NHID*4);
    float*    partial = (float*)alloc(256);
    float*    bias0 = (float*)alloc((size_t)NGS*4);
    float*    bias1 = (float*)alloc((size_t)NGS*4);
    unsigned* hbf   = (unsigned*)alloc((size_t)2*2*NB*NH*4);
    unsigned* flags = (unsigned*)alloc((size_t)2*NCHUNK*16*4);

    float* em_out   = (float*)d_out;
    float* dec_out  = em_out + (size_t)NBS*NT;
    float* loss_out = dec_out + NBS;

    // 1. pack weights into hi/lo planes (cat fwd|bwd rows)
    k_pack_w<<<(NG4*NIN0P+255)/256, 256, 0, stream>>>(l0f_Wih, w0h, w0l, NG4, NIN0, NIN0P);
    k_pack_w<<<(NG4*NIN0P+255)/256, 256, 0, stream>>>(l0b_Wih, w0h + (size_t)NG4*NIN0P, w0l + (size_t)NG4*NIN0P, NG4, NIN0, NIN0P);
    k_pack_w<<<(NG4*NIN1+255)/256, 256, 0, stream>>>(l1f_Wih, w1h, w1l, NG4, NIN1, NIN1);
    k_pack_w<<<(NG4*NIN1+255)/256, 256, 0, stream>>>(l1b_Wih, w1h + (size_t)NG4*NIN1, w1l + (size_t)NG4*NIN1, NG4, NIN1, NIN1);
    k_pack_w<<<(NHID*NIN1+255)/256, 256, 0, stream>>>(lin1W, wlh, wll, NHID, NIN1, NIN1);
    // cat biases
    hipMemcpyAsync(bias0,       l0f_b, NG4*4, hipMemcpyDeviceToDevice, stream);
    hipMemcpyAsync(bias0 + NG4, l0b_b, NG4*4, hipMemcpyDeviceToDevice, stream);
    hipMemcpyAsync(bias1,       l1f_b, NG4*4, hipMemcpyDeviceToDevice, stream);
    hipMemcpyAsync(bias1 + NG4, l1b_b, NG4*4, hipMemcpyDeviceToDevice, stream);
    // 2. features (hi/lo planes)
    k_features<<<NBS, 128, 0, stream>>>(x_word, x_pos, x_char, x_enr, wembW, cembW, cnnW, cnnb, xh, xl);
    // 3. layer-0 fused input projection (both dirs, N=4096)
    k_gemm_hl<<<dim3(NBS/128, NGS/128), 256, 0, stream>>>(xh, xl, w0h, w0l, bias0, zxcat, NBS, NGS, NIN0P);
    // 4. layer-0 recurrence
    hipMemsetAsync(flags, 0, (size_t)2*NCHUNK*16*4, stream);
    k_lstm_layer<<<dim3(NCHUNK, 2), 512, 0, stream>>>(zxcat, l0f_Whh, l0b_Whh, h0h, h0l, hbf, flags);
    // 5. layer-1 fused input projection
    k_gemm_hl<<<dim3(NBS/128, NGS/128), 256, 0, stream>>>(h0h, h0l, w1h, w1l, bias1, zxcat, NBS, NGS, NIN1);
    // 6. layer-1 recurrence
    hipMemsetAsync(flags, 0, (size_t)2*NCHUNK*16*4, stream);
    k_lstm_layer<<<dim3(NCHUNK, 2), 512, 0, stream>>>(zxcat, l1f_Whh, l1b_Whh, h1h, h1l, hbf, flags);
    // 7. head
    k_gemm_hl<<<dim3(NBS/128, NHID/128), 256, 0, stream>>>(h1h, h1l, wlh, wll, lin1b, hid1, NBS, NHID, NIN1);
    k_lin2<<<(NBS*NT+255)/256, 256, 0, stream>>>(hid1, lin2W, lin2b, em_out);
    // 8. CRF (fused viterbi + nll)
    k_crf<<<NB, 64, 0, stream>>>(em_out, y_word, crf_s, crf_e, crf_tr, dec_out, partial);
    k_loss_final<<<1, 64, 0, stream>>>(partial, loss_out);
}

// Round 15
// 3610.547 us; speedup vs baseline: 1.7794x; 1.1726x over previous
//
#include <hip/hip_runtime.h>
#include <hip/hip_bf16.h>
#include <math.h>

// ---- problem dims ----
constexpr int NB   = 32;
constexpr int NS   = 256;
constexpr int NLC  = 16;
constexpr int NWD  = 256;
constexpr int NCD  = 124;
constexpr int NCO  = 32;
constexpr int NPOS = 36;
constexpr int NENR = 7;
constexpr int NH   = 512;
constexpr int NT   = 18;
constexpr int NIN0 = 331;
constexpr int NIN0P= 352;    // padded to x32
constexpr int NIN1 = 1024;
constexpr int NBS  = NB*NS;  // 8192
constexpr int NG4  = 4*NH;   // 2048
constexpr int NGS  = 4096;   // fused zx row stride (fwd 2048 | bwd 2048)
constexpr int NHID = 128;
constexpr int NCHUNK = 16;   // unit-chunks per dir (32 units each)

typedef __attribute__((ext_vector_type(8))) short short8v;
typedef __attribute__((ext_vector_type(4))) float f32x4;
typedef __attribute__((address_space(3))) unsigned lds_u32;
typedef __attribute__((address_space(1))) const unsigned glb_u32;

__device__ __forceinline__ float sigmoidf_(float x){ return 1.0f/(1.0f+expf(-x)); }
__device__ __forceinline__ short f2bf(float f) {
    union { __hip_bfloat16 h; short s; } u;
    u.h = __float2bfloat16(f);
    return u.s;
}
__device__ __forceinline__ float bf2f(short s) {
    union { unsigned u; float f; } v;
    v.u = ((unsigned)(unsigned short)s) << 16;
    return v.f;
}
__device__ __forceinline__ unsigned packbf3(float v) {
    short hi = f2bf(v);
    short lo = f2bf(v - bf2f(hi));
    return ((unsigned)(unsigned short)hi << 16) | (unsigned short)lo;
}
// 8 packed u32 -> hi/lo bf16 fragments (lstm exchange path only)
__device__ __forceinline__ void unpack8(const unsigned* w, short8v& hi, short8v& lo) {
    union U { short8v s; unsigned u[4]; } H, L;
    #pragma unroll
    for (int i = 0; i < 4; i++) {
        H.u[i] = (w[2*i+1] & 0xFFFF0000u) | (w[2*i] >> 16);
        L.u[i] = (w[2*i+1] << 16) | (w[2*i] & 0xFFFFu);
    }
    hi = H.s; lo = L.s;
}
// relaxed agent-scope ops (sc1 path, no cache maintenance) — proven in r6
__device__ __forceinline__ unsigned ld_sc1(const unsigned* p) {
    return __hip_atomic_load(p, __ATOMIC_RELAXED, __HIP_MEMORY_SCOPE_AGENT);
}
__device__ __forceinline__ void st_sc1(unsigned* p, unsigned v) {
    __hip_atomic_store(p, v, __ATOMIC_RELAXED, __HIP_MEMORY_SCOPE_AGENT);
}

// -------- features: word embed + char CNN + concat + relu -> hi/lo bf16 planes ----
__global__ __launch_bounds__(128) void k_features(const int* __restrict__ x_word,
    const float* __restrict__ x_pos, const int* __restrict__ x_char,
    const float* __restrict__ x_enr, const float* __restrict__ wembW,
    const float* __restrict__ cembW, const float* __restrict__ cnnW,
    const float* __restrict__ cnnb,
    unsigned short* __restrict__ xh, unsigned short* __restrict__ xl)
{
    __shared__ float ce[NLC][NCD];     // 7.9 KB
    __shared__ float wT[310*33];       // 40.9 KB: half of cnnW, [ck][o] padded
    __shared__ float cv[NCO][14];
    __shared__ float cpool[NCO];
    int n = blockIdx.x;
    int tid = threadIdx.x;
    for (int i = tid; i < NLC*NCD; i += 128) {
        int l = i / NCD, c = i % NCD;
        ce[l][c] = cembW[x_char[n*NLC + l]*NCD + c];
    }
    float acc3[3] = {0.f, 0.f, 0.f};
    #pragma unroll
    for (int half = 0; half < 2; half++) {
        int csta = half*62;
        __syncthreads();
        for (int i = tid; i < 310*32; i += 128) {
            int o = i / 310, ck = i - o*310;
            wT[ck*33 + o] = cnnW[o*(NCD*5) + csta*5 + ck];
        }
        __syncthreads();
        #pragma unroll
        for (int q = 0; q < 3; q++) {
            int p = tid + q*128;
            int o = p & 31, t = p >> 5;
            float acc = acc3[q];
            for (int c = 0; c < 62; c++) {
                #pragma unroll
                for (int k = 0; k < 5; k++)
                    acc += ce[t+k][csta + c] * wT[(c*5+k)*33 + o];
            }
            acc3[q] = acc;
        }
    }
    #pragma unroll
    for (int q = 0; q < 3; q++) {
        int p = tid + q*128;
        cv[p & 31][p >> 5] = acc3[q];
    }
    __syncthreads();
    if (tid < NCO) {
        float m = cv[tid][0];
        #pragma unroll
        for (int t = 1; t < 12; t++) m = fmaxf(m, cv[tid][t]);
        cpool[tid] = m + cnnb[tid];
    }
    __syncthreads();
    int widx = x_word[n];
    for (int j = tid; j < NIN0P; j += 128) {
        float v;
        if (j < NWD)            v = wembW[(size_t)widx*NWD + j];
        else if (j < NWD+NPOS)  v = x_pos[n*NPOS + (j-NWD)];
        else if (j < NWD+NPOS+NCO) v = cpool[j-(NWD+NPOS)];
        else if (j < NIN0)      v = x_enr[n*NENR + (j-(NWD+NPOS+NCO))];
        else                    v = 0.f;
        v = fmaxf(v, 0.f);
        short hi = f2bf(v);
        xh[(size_t)n*NIN0P + j] = (unsigned short)hi;
        xl[(size_t)n*NIN0P + j] = (unsigned short)f2bf(v - bf2f(hi));
    }
}

// -------- pack f32 weight [N][Ksrc] -> hi/lo bf16 planes [N][Kdst] (zero pad) ----
__global__ void k_pack_w(const float* __restrict__ W,
                         unsigned short* __restrict__ Wh, unsigned short* __restrict__ Wl,
                         int N, int Ksrc, int Kdst)
{
    int idx = blockIdx.x*256 + threadIdx.x;
    if (idx >= N*Kdst) return;
    int n = idx / Kdst, k = idx % Kdst;
    float v = (k < Ksrc) ? W[(size_t)n*Ksrc + k] : 0.f;
    short hi = f2bf(v);
    Wh[idx] = (unsigned short)hi;
    Wl[idx] = (unsigned short)f2bf(v - bf2f(hi));
}

// -------- split-plane bf16x3 MFMA GEMM: C[M,N] = A@W^T + bias ----------------
// r15: staging via global_load_lds width=16 (m97/m151 pattern: 874 vs 646 TF
// reg-staged at 128^2). Linear LDS dest; the 16B-unit XOR swizzle moves to the
// per-lane GLOBAL source address (same 64B segments -> coalescing kept; same
// final LDS layout -> MFMA read path unchanged). Double-buffer, ONE barrier/kt:
// barrier -> issue stage(kt+1 -> buf^1) -> compute(buf cur).
constexpr int HBK = 32;
__global__ __launch_bounds__(256, 2) void k_gemm_hl(
    const unsigned short* __restrict__ Ah, const unsigned short* __restrict__ Al,
    const unsigned short* __restrict__ Bh, const unsigned short* __restrict__ Bl,
    const float* __restrict__ bias, float* __restrict__ C,
    int M, int N, int K)
{
    __shared__ unsigned short sA[2][2][128*HBK];   // [buf][hi/lo] 16 KB
    __shared__ unsigned short sB[2][2][128*HBK];
    int bx = blockIdx.x, by = blockIdx.y;
    {
        int nMb = gridDim.x, nNb = gridDim.y;
        if (((nMb | nNb) & 3) == 0) {
            int lin = by * nMb + bx;
            int sid = lin >> 4, rem = lin & 15;
            int spr = nNb >> 2;
            int sm = sid / spr, sn = sid - sm*spr;
            bx = sm*4 + (rem >> 2);
            by = sn*4 + (rem & 3);
        }
    }
    int bm = bx*128, bn = by*128;
    int tid = threadIdx.x;
    int l = tid & 63, wv = tid >> 6;
    int wm = wv >> 1, wn = wv & 1;
    int lr = l & 15, lk = l >> 4;

    // wave wv stages plane wv: 0->Ah, 1->Al, 2->Bh, 3->Bl
    const unsigned short* gplane = (wv == 0) ? Ah : (wv == 1) ? Al : (wv == 2) ? Bh : Bl;
    int gbase = (wv < 2) ? bm : bn;
    unsigned short* lplane0 = (wv == 0) ? sA[0][0] : (wv == 1) ? sA[0][1]
                           : (wv == 2) ? sB[0][0] : sB[0][1];
    unsigned short* lplane1 = (wv == 0) ? sA[1][0] : (wv == 1) ? sA[1][1]
                           : (wv == 2) ? sB[1][0] : sB[1][1];
    int lrow = l >> 2;                 // 0..15 within 16-row group
    int gu = (l & 3);                  // unit before swizzle

    auto stage = [&](int kt, int buf) {
        unsigned short* lp0 = buf ? lplane1 : lplane0;
        #pragma unroll
        for (int rr = 0; rr < 8; rr++) {
            int row = rr*16 + lrow;
            int guS = gu ^ (row & 3);  // pre-swizzled global source unit
            glb_u32* gp = (glb_u32*)(gplane + (size_t)(gbase + row)*K + (size_t)kt*HBK + guS*8);
            lds_u32* lp = (lds_u32*)(lp0 + (rr*16)*HBK);   // wave-uniform base
            __builtin_amdgcn_global_load_lds(gp, lp, 16, 0, 0);
        }
    };

    f32x4 acc[4][4];
    #pragma unroll
    for (int i = 0; i < 4; i++)
        #pragma unroll
        for (int j = 0; j < 4; j++) acc[i][j] = (f32x4){0.f,0.f,0.f,0.f};

    int KT = K / HBK;
    stage(0, 0);
    int cur = 0;
    for (int kt = 0; kt < KT; kt++) {
        __syncthreads();                   // drains stage(kt); buf^1 readers done
        if (kt+1 < KT) stage(kt+1, cur^1); // async into the other buffer
        short8v fAh[4], fAl[4], fBh[4], fBl[4];
        #pragma unroll
        for (int f = 0; f < 4; f++) {
            int ra = wm*64 + f*16 + lr, ua = (lk ^ (ra & 3))*8;
            fAh[f] = *(const short8v*)&sA[cur][0][ra*HBK + ua];
            fAl[f] = *(const short8v*)&sA[cur][1][ra*HBK + ua];
            int rb = wn*64 + f*16 + lr, ub = (lk ^ (rb & 3))*8;
            fBh[f] = *(const short8v*)&sB[cur][0][rb*HBK + ub];
            fBl[f] = *(const short8v*)&sB[cur][1][rb*HBK + ub];
        }
        #pragma unroll
        for (int i = 0; i < 4; i++)
            #pragma unroll
            for (int j = 0; j < 4; j++) {
                acc[i][j] = __builtin_amdgcn_mfma_f32_16x16x32_bf16(fAh[i], fBh[j], acc[i][j], 0, 0, 0);
                acc[i][j] = __builtin_amdgcn_mfma_f32_16x16x32_bf16(fAl[i], fBh[j], acc[i][j], 0, 0, 0);
                acc[i][j] = __builtin_amdgcn_mfma_f32_16x16x32_bf16(fAh[i], fBl[j], acc[i][j], 0, 0, 0);
            }
        cur ^= 1;
    }
    #pragma unroll
    for (int i = 0; i < 4; i++) {
        int m0 = bm + wm*64 + i*16 + lk*4;
        #pragma unroll
        for (int j = 0; j < 4; j++) {
            int n0 = bn + wn*64 + j*16 + lr;
            float bv = bias[n0];
            #pragma unroll
            for (int q = 0; q < 4; q++)
                C[(size_t)(m0+q)*N + n0] = acc[i][j][q] + bv;
        }
    }
}

// ---------------- persistent LSTM layer (r12 structure, best measured) ----------
__global__ __launch_bounds__(512, 2) void k_lstm_layer(
    const float* __restrict__ zxcat,
    const float* __restrict__ Whh_f, const float* __restrict__ Whh_b,
    unsigned short* __restrict__ h_hi, unsigned short* __restrict__ h_lo,
    unsigned* __restrict__ hbf, unsigned* __restrict__ flags)
{
    int chunk = blockIdx.x;
    int dir   = blockIdx.y;
    int tid = threadIdx.x;
    int wv = tid >> 6, l = tid & 63;
    int g  = wv & 3;
    int ks = wv >> 2;
    int lr = l & 15, lk = l >> 4;
    const float* zx  = zxcat + dir*NG4;
    const float* Whh = dir ? Whh_b : Whh_f;
    unsigned* hb = hbf + (size_t)dir * (2*NB*NH);
    unsigned* flag = flags + (size_t)dir * NCHUNK * 16;

    short8v bwh[2][8], bwl[2][8];
    #pragma unroll
    for (int uh = 0; uh < 2; uh++) {
        const float* wrow = Whh + ((size_t)(g*NH + chunk*32 + uh*16 + lr))*NH + ks*256 + lk*8;
        #pragma unroll
        for (int kt = 0; kt < 8; kt++) {
            float u[8];
            *(float4*)&u[0] = *(const float4*)(wrow + kt*32);
            *(float4*)&u[4] = *(const float4*)(wrow + kt*32 + 4);
            short8v sh, sl;
            #pragma unroll
            for (int j = 0; j < 8; j++) {
                short hi = f2bf(u[j]);
                sh[j] = hi;
                sl[j] = f2bf(u[j] - bf2f(hi));
            }
            bwh[uh][kt] = sh; bwl[uh][kt] = sl;
        }
    }

    __shared__ unsigned hstage[32*516];
    __shared__ float zsh[2][4][32][33];
    float c0 = 0.f, c1 = 0.f;

    for (int t = 0; t < NS; t++) {
        int t_eff = dir ? (NS-1-t) : t;

        float pz[2][4];
        #pragma unroll
        for (int cc = 0; cc < 2; cc++) {
            int cell = tid + cc*512, b = cell >> 5, u = cell & 31;
            const float* zr = zx + ((size_t)(b*NS + t_eff))*NGS + chunk*32 + u;
            #pragma unroll
            for (int g2 = 0; g2 < 4; g2++) pz[cc][g2] = zr[g2*NH];
        }

        if (t > 0) {
            {
                const unsigned* fp = &flag[(l & 15)*16];
                unsigned v;
                do { v = ld_sc1(fp); } while (!__all((int)(v >= (unsigned)t)));
                asm volatile("" ::: "memory");
            }
            const unsigned* hp = hb + ((t-1)&1)*(NB*NH);
            unsigned sv[32];
            #pragma unroll
            for (int i = 0; i < 32; i++) sv[i] = ld_sc1(hp + i*512 + tid);
            #pragma unroll
            for (int i = 0; i < 32; i++) hstage[i*516 + tid] = sv[i];
        }
        __syncthreads();   // barrier A: stage visible

        f32x4 acc[2][2][3];
        #pragma unroll
        for (int bh = 0; bh < 2; bh++)
            #pragma unroll
            for (int uh = 0; uh < 2; uh++)
                #pragma unroll
                for (int q = 0; q < 3; q++) acc[bh][uh][q] = (f32x4){0.f,0.f,0.f,0.f};
        if (t > 0) {
            #pragma unroll
            for (int kt = 0; kt < 8; kt++) {
                short8v ah[2], al[2];
                #pragma unroll
                for (int bh = 0; bh < 2; bh++) {
                    unsigned w8[8];
                    const unsigned* sp = hstage + (bh*16+lr)*516 + ks*256 + kt*32 + lk*8;
                    *(uint4*)&w8[0] = *(const uint4*)sp;
                    *(uint4*)&w8[4] = *(const uint4*)(sp+4);
                    unpack8(w8, ah[bh], al[bh]);
                }
                #pragma unroll
                for (int bh = 0; bh < 2; bh++)
                    #pragma unroll
                    for (int uh = 0; uh < 2; uh++) {
                        acc[bh][uh][0] = __builtin_amdgcn_mfma_f32_16x16x32_bf16(ah[bh], bwh[uh][kt], acc[bh][uh][0], 0, 0, 0);
                        acc[bh][uh][1] = __builtin_amdgcn_mfma_f32_16x16x32_bf16(al[bh], bwh[uh][kt], acc[bh][uh][1], 0, 0, 0);
                        acc[bh][uh][2] = __builtin_amdgcn_mfma_f32_16x16x32_bf16(ah[bh], bwl[uh][kt], acc[bh][uh][2], 0, 0, 0);
                    }
            }
        }
        #pragma unroll
        for (int bh = 0; bh < 2; bh++)
            #pragma unroll
            for (int uh = 0; uh < 2; uh++)
                #pragma unroll
                for (int j = 0; j < 4; j++)
                    zsh[ks][g][bh*16 + lk*4 + j][uh*16 + lr] =
                        acc[bh][uh][0][j] + acc[bh][uh][1][j] + acc[bh][uh][2][j];
        __syncthreads();   // barrier B: zsh ready

        unsigned hq0 = 0, hq1 = 0;
        #pragma unroll
        for (int cc = 0; cc < 2; cc++) {
            int cell = tid + cc*512, b = cell >> 5, u = cell & 31;
            float zi = pz[cc][0] + zsh[0][0][b][u] + zsh[1][0][b][u];
            float zf = pz[cc][1] + zsh[0][1][b][u] + zsh[1][1][b][u];
            float zg = pz[cc][2] + zsh[0][2][b][u] + zsh[1][2][b][u];
            float zo = pz[cc][3] + zsh[0][3][b][u] + zsh[1][3][b][u];
            float cold = cc ? c1 : c0;
            float cn = sigmoidf_(zf)*cold + sigmoidf_(zi)*tanhf(zg);
            float hn = sigmoidf_(zo)*tanhf(cn);
            unsigned pk = packbf3(hn);
            if (cc) { c1 = cn; hq1 = pk; } else { c0 = cn; hq0 = pk; }
            st_sc1(&hb[(size_t)(t&1)*(NB*NH) + b*NH + chunk*32 + u], pk);
        }
        __syncthreads();   // barrier C: all waves' stores drained
        if (tid == 0)
            st_sc1(&flag[chunk*16], (unsigned)(t+1));
        #pragma unroll
        for (int cc = 0; cc < 2; cc++) {
            int cell = tid + cc*512, b = cell >> 5, u = cell & 31;
            unsigned pk = cc ? hq1 : hq0;
            size_t o = ((size_t)(b*NS + t_eff))*NIN1 + dir*NH + chunk*32 + u;
            h_hi[o] = (unsigned short)(pk >> 16);
            h_lo[o] = (unsigned short)(pk & 0xFFFFu);
        }
    }
}

// ---------------- emissions: em = hid1 @ lin2W^T + b2 ----------------
__global__ __launch_bounds__(256) void k_lin2(const float* __restrict__ hid,
    const float* __restrict__ W2, const float* __restrict__ b2, float* __restrict__ em)
{
    int flat = blockIdx.x*256 + threadIdx.x;
    if (flat >= NBS*NT) return;
    int m = flat / NT, j = flat % NT;
    const float* hr = hid + (size_t)m*NHID;
    const float* wr = W2 + j*NHID;
    float acc = b2[j];
    #pragma unroll 8
    for (int k = 0; k < NHID; k += 4) {
        float4 h4 = *(const float4*)(hr+k);
        float4 w4 = *(const float4*)(wr+k);
        acc += h4.x*w4.x + h4.y*w4.y + h4.z*w4.z + h4.w*w4.w;
    }
    em[flat] = acc;
}

// ---------------- fused CRF: viterbi decode + NLL forward in one pass ---------
__global__ __launch_bounds__(64) void k_crf(const float* __restrict__ em,
    const int* __restrict__ tags, const float* __restrict__ start,
    const float* __restrict__ endv, const float* __restrict__ trans,
    float* __restrict__ dec, float* __restrict__ partial)
{
    __shared__ float tr[NT][NT];
    __shared__ float vsc[NT], nsc[NT];
    __shared__ unsigned char hist[NS][NT];
    __shared__ float numsh;
    int b = blockIdx.x, tid = threadIdx.x;
    for (int i = tid; i < NT*NT; i += 64) tr[i/NT][i%NT] = trans[i];
    if (tid < NT) {
        float e0 = em[((size_t)b*NS)*NT + tid];
        vsc[tid] = start[tid] + e0;
        nsc[tid] = start[tid] + e0;
    }
    __syncthreads();
    const int* tg = tags + b*NS;
    float num = 0.f;
    for (int t = 1; t < NS; t++) {
        float nv_v = 0.f, nv_n = 0.f;
        if (tid < NT) {
            float emv = em[((size_t)b*NS + t)*NT + tid];
            float best = -1e30f; int bi = 0;
            float m = -1e30f;
            for (int i = 0; i < NT; i++) {
                float v = vsc[i] + tr[i][tid];
                if (v > best) { best = v; bi = i; }   // strict > = first max
                m = fmaxf(m, nsc[i] + tr[i][tid]);
            }
            hist[t][tid] = (unsigned char)bi;
            nv_v = best + emv;
            float s = 0.f;
            for (int i = 0; i < NT; i++) s += expf(nsc[i] + tr[i][tid] - m);
            nv_n = m + logf(s) + emv;
        } else if (tid == 32) {
            num += tr[tg[t-1]][tg[t]] + em[((size_t)b*NS + t)*NT + tg[t]];
        }
        __syncthreads();
        if (tid < NT) { vsc[tid] = nv_v; nsc[tid] = nv_n; }
        __syncthreads();
    }
    if (tid == 32) numsh = num;
    __syncthreads();
    if (tid == 0) {
        float bv = vsc[0] + endv[0]; int tag = 0;
        for (int j = 1; j < NT; j++) { float v = vsc[j] + endv[j]; if (v > bv) { bv = v; tag = j; } }
        dec[b*NS + NS-1] = (float)tag;
        for (int t = NS-1; t >= 1; t--) { tag = hist[t][tag]; dec[b*NS + t-1] = (float)tag; }
        float m = -1e30f;
        for (int j = 0; j < NT; j++) m = fmaxf(m, nsc[j] + endv[j]);
        float s = 0.f;
        for (int j = 0; j < NT; j++) s += expf(nsc[j] + endv[j] - m);
        float logZ = m + logf(s);
        float numer = start[tg[0]] + em[((size_t)b*NS)*NT + tg[0]] + numsh + endv[tg[NS-1]];
        partial[b] = -(numer - logZ);
    }
}

__global__ void k_loss_final(const float* __restrict__ partial, float* __restrict__ loss)
{
    if (threadIdx.x == 0 && blockIdx.x == 0) {
        float s = 0.f;
        for (int b = 0; b < NB; b++) s += partial[b];
        *loss = s / (float)(NB*NS);
    }
}

extern "C" void kernel_launch(void* const* d_in, const int* in_sizes, int n_in,
                              void* d_out, int out_size, void* d_ws, size_t ws_size,
                              hipStream_t stream)
{
    const int*   x_word = (const int*)d_in[0];
    const float* x_pos  = (const float*)d_in[1];
    const int*   x_char = (const int*)d_in[2];
    const float* x_enr  = (const float*)d_in[3];
    const int*   y_word = (const int*)d_in[5];
    const float* wembW  = (const float*)d_in[6];
    const float* cembW  = (const float*)d_in[7];
    const float* cnnW   = (const float*)d_in[8];
    const float* cnnb   = (const float*)d_in[9];
    const float* lin1W  = (const float*)d_in[10];
    const float* lin1b  = (const float*)d_in[11];
    const float* lin2W  = (const float*)d_in[12];
    const float* lin2b  = (const float*)d_in[13];
    const float* crf_s  = (const float*)d_in[14];
    const float* crf_e  = (const float*)d_in[15];
    const float* crf_tr = (const float*)d_in[16];
    const float* l0f_Wih = (const float*)d_in[17];
    const float* l0f_Whh = (const float*)d_in[18];
    const float* l0f_b   = (const float*)d_in[19];
    const float* l0b_Wih = (const float*)d_in[20];
    const float* l0b_Whh = (const float*)d_in[21];
    const float* l0b_b   = (const float*)d_in[22];
    const float* l1f_Wih = (const float*)d_in[23];
    const float* l1f_Whh = (const float*)d_in[24];
    const float* l1f_b   = (const float*)d_in[25];
    const float* l1b_Wih = (const float*)d_in[26];
    const float* l1b_Whh = (const float*)d_in[27];
    const float* l1b_b   = (const float*)d_in[28];

    char* wsb = (char*)d_ws;
    size_t off = 0;
    auto alloc = [&](size_t bytes) { char* p = wsb + off; off += (bytes + 255) & ~(size_t)255; return p; };
    unsigned short* xh  = (unsigned short*)alloc((size_t)NBS*NIN0P*2);
    unsigned short* xl  = (unsigned short*)alloc((size_t)NBS*NIN0P*2);
    unsigned short* w0h = (unsigned short*)alloc((size_t)NGS*NIN0P*2);
    unsigned short* w0l = (unsigned short*)alloc((size_t)NGS*NIN0P*2);
    unsigned short* w1h = (unsigned short*)alloc((size_t)NGS*NIN1*2);
    unsigned short* w1l = (unsigned short*)alloc((size_t)NGS*NIN1*2);
    unsigned short* wlh = (unsigned short*)alloc((size_t)NHID*NIN1*2);
    unsigned short* wll = (unsigned short*)alloc((size_t)NHID*NIN1*2);
    float*    zxcat = (float*)alloc((size_t)NBS*NGS*4);
    unsigned short* h0h = (unsigned short*)alloc((size_t)NBS*NIN1*2);
    unsigned short* h0l = (unsigned short*)alloc((size_t)NBS*NIN1*2);
    unsigned short* h1h = (unsigned short*)alloc((size_t)NBS*NIN1*2);
    unsigned short* h1l = (unsigned short*)alloc((size_t)NBS*NIN1*2);
    float*    hid1  = (float*)alloc((size_t)NBS*NHID*4);
    float*    partial = (float*)alloc(256);
    float*    bias0 = (float*)alloc((size_t)NGS*4);
    float*    bias1 = (float*)alloc((size_t)NGS*4);
    unsigned* hbf   = (unsigned*)alloc((size_t)2*2*NB*NH*4);
    unsigned* flags = (unsigned*)alloc((size_t)2*NCHUNK*16*4);

    float* em_out   = (float*)d_out;
    float* dec_out  = em_out + (size_t)NBS*NT;
    float* loss_out = dec_out + NBS;

    // 1. pack weights into hi/lo planes (cat fwd|bwd rows)
    k_pack_w<<<(NG4*NIN0P+255)/256, 256, 0, stream>>>(l0f_Wih, w0h, w0l, NG4, NIN0, NIN0P);
    k_pack_w<<<(NG4*NIN0P+255)/256, 256, 0, stream>>>(l0b_Wih, w0h + (size_t)NG4*NIN0P, w0l + (size_t)NG4*NIN0P, NG4, NIN0, NIN0P);
    k_pack_w<<<(NG4*NIN1+255)/256, 256, 0, stream>>>(l1f_Wih, w1h, w1l, NG4, NIN1, NIN1);
    k_pack_w<<<(NG4*NIN1+255)/256, 256, 0, stream>>>(l1b_Wih, w1h + (size_t)NG4*NIN1, w1l + (size_t)NG4*NIN1, NG4, NIN1, NIN1);
    k_pack_w<<<(NHID*NIN1+255)/256, 256, 0, stream>>>(lin1W, wlh, wll, NHID, NIN1, NIN1);
    // cat biases
    hipMemcpyAsync(bias0,       l0f_b, NG4*4, hipMemcpyDeviceToDevice, stream);
    hipMemcpyAsync(bias0 + NG4, l0b_b, NG4*4, hipMemcpyDeviceToDevice, stream);
    hipMemcpyAsync(bias1,       l1f_b, NG4*4, hipMemcpyDeviceToDevice, stream);
    hipMemcpyAsync(bias1 + NG4, l1b_b, NG4*4, hipMemcpyDeviceToDevice, stream);
    // 2. features (hi/lo planes)
    k_features<<<NBS, 128, 0, stream>>>(x_word, x_pos, x_char, x_enr, wembW, cembW, cnnW, cnnb, xh, xl);
    // 3. layer-0 fused input projection (both dirs, N=4096)
    k_gemm_hl<<<dim3(NBS/128, NGS/128), 256, 0, stream>>>(xh, xl, w0h, w0l, bias0, zxcat, NBS, NGS, NIN0P);
    // 4. layer-0 recurrence
    hipMemsetAsync(flags, 0, (size_t)2*NCHUNK*16*4, stream);
    k_lstm_layer<<<dim3(NCHUNK, 2), 512, 0, stream>>>(zxcat, l0f_Whh, l0b_Whh, h0h, h0l, hbf, flags);
    // 5. layer-1 fused input projection
    k_gemm_hl<<<dim3(NBS/128, NGS/128), 256, 0, stream>>>(h0h, h0l, w1h, w1l, bias1, zxcat, NBS, NGS, NIN1);
    // 6. layer-1 recurrence
    hipMemsetAsync(flags, 0, (size_t)2*NCHUNK*16*4, stream);
    k_lstm_layer<<<dim3(NCHUNK, 2), 512, 0, stream>>>(zxcat, l1f_Whh, l1b_Whh, h1h, h1l, hbf, flags);
    // 7. head
    k_gemm_hl<<<dim3(NBS/128, NHID/128), 256, 0, stream>>>(h1h, h1l, wlh, wll, lin1b, hid1, NBS, NHID, NIN1);
    k_lin2<<<(NBS*NT+255)/256, 256, 0, stream>>>(hid1, lin2W, lin2b, em_out);
    // 8. CRF (fused viterbi + nll)
    k_crf<<<NB, 64, 0, stream>>>(em_out, y_word, crf_s, crf_e, crf_tr, dec_out, partial);
    k_loss_final<<<1, 64, 0, stream>>>(partial, loss_out);
}